// Round 1
// baseline (2459.035 us; speedup 1.0000x reference)
//
#include <hip/hip_runtime.h>
#include <hip/hip_bf16.h>
#include <float.h>

#define BB 4
#define SS 2048
#define DD 1024
#define HH 16
#define DP 64
#define NROW (BB*HH*SS)   /* 131072 attention rows (b,h,q) */
#define MARGIN 1e-3f      /* unscaled-score ambiguity margin (~100x fp32 filter error) */

// ---------------------------------------------------------------------------
// Kernel 1: fp32 projection GEMM.  C = x(8192x1024) @ W(1024x1024) for
// W in {Wq, Wk, Wv} (blockIdx.z).  Epilogue writes head-split layouts:
//   Q: [B*H][S][64]   Kt: [B*H][64][S] (transposed for filter)   V: [B*H][S][64]
// ---------------------------------------------------------------------------
__global__ __launch_bounds__(256) void proj_kernel(
    const float* __restrict__ x, const float* __restrict__ Wq,
    const float* __restrict__ Wk, const float* __restrict__ Wv,
    float* __restrict__ Q, float* __restrict__ Kt, float* __restrict__ V)
{
  const int z = blockIdx.z;
  const float* __restrict__ W = (z == 0) ? Wq : (z == 1 ? Wk : Wv);
  __shared__ float As[16][132];   // x tile, transposed: As[k][m]
  __shared__ float Bs[16][132];   // W tile: Bs[k][n]
  const int row0 = blockIdx.x * 128;
  const int col0 = blockIdx.y * 128;
  const int tid = threadIdx.x;
  const int ty = tid >> 4, tx = tid & 15;

  float acc[8][8];
  #pragma unroll
  for (int i = 0; i < 8; ++i)
    #pragma unroll
    for (int j = 0; j < 8; ++j) acc[i][j] = 0.f;

  for (int t = 0; t < 64; ++t) {
    const int k0 = t * 16;
    #pragma unroll
    for (int i = 0; i < 2; ++i) {
      int e = tid + i * 256;          // 0..511
      int m = e >> 2;                 // 0..127
      int k4 = (e & 3) << 2;          // 0,4,8,12
      float4 v = *(const float4*)(x + (size_t)(row0 + m) * DD + k0 + k4);
      As[k4 + 0][m] = v.x; As[k4 + 1][m] = v.y;
      As[k4 + 2][m] = v.z; As[k4 + 3][m] = v.w;
    }
    #pragma unroll
    for (int i = 0; i < 2; ++i) {
      int e = tid + i * 256;
      int k = e >> 5;                 // 0..15
      int n4 = (e & 31) << 2;         // 0..124
      *(float4*)&Bs[k][n4] = *(const float4*)(W + (size_t)(k0 + k) * DD + col0 + n4);
    }
    __syncthreads();
    #pragma unroll
    for (int k = 0; k < 16; ++k) {
      float4 a0 = *(const float4*)&As[k][ty * 8];
      float4 a1 = *(const float4*)&As[k][ty * 8 + 4];
      float4 b0 = *(const float4*)&Bs[k][tx * 8];
      float4 b1 = *(const float4*)&Bs[k][tx * 8 + 4];
      float av[8] = {a0.x, a0.y, a0.z, a0.w, a1.x, a1.y, a1.z, a1.w};
      float bv[8] = {b0.x, b0.y, b0.z, b0.w, b1.x, b1.y, b1.z, b1.w};
      #pragma unroll
      for (int i = 0; i < 8; ++i)
        #pragma unroll
        for (int j = 0; j < 8; ++j) acc[i][j] = fmaf(av[i], bv[j], acc[i][j]);
    }
    __syncthreads();
  }

  #pragma unroll
  for (int i = 0; i < 8; ++i) {
    const int m = row0 + ty * 8 + i;
    const int b = m >> 11, s = m & 2047;
    #pragma unroll
    for (int j = 0; j < 8; ++j) {
      const int n = col0 + tx * 8 + j;
      const int h = n >> 6, d = n & 63;
      const size_t bh = (size_t)(b * HH + h);
      if (z == 1) {
        Kt[(bh * DP + d) * SS + s] = acc[i][j];
      } else {
        float* dst = (z == 0) ? Q : V;
        dst[(bh * SS + s) * DP + d] = acc[i][j];
      }
    }
  }
}

// ---------------------------------------------------------------------------
// Kernel 2: masked-argmin filter.  One thread per (b,h,q) row; block = 256
// rows sharing one (b,h).  K tiles staged in LDS, read broadcast.  Tracks
// min1 and all candidates within MARGIN of the running min (superset of the
// final margin set).  Rows with >=2 final candidates go to the refine list.
// ---------------------------------------------------------------------------
__global__ __launch_bounds__(256) void filter_kernel(
    const float* __restrict__ Q, const float* __restrict__ Kt,
    const int* __restrict__ mask, int* __restrict__ idx,
    int* __restrict__ ambig_rows, int* __restrict__ ambig_cnt,
    int* __restrict__ cand, int* __restrict__ cand_cnt)
{
  __shared__ float Ks[64][128];   // 32 KiB, d-major
  __shared__ int ms[SS];          // 8 KiB mask for this batch
  const int bh = blockIdx.x >> 3;           // 8 blocks per (b,h)
  const int q0 = (blockIdx.x & 7) << 8;
  const int b = bh >> 4;
  const int t = threadIdx.x;
  const int row = (bh << 11) + q0 + t;

  for (int i = t; i < SS; i += 256) ms[i] = mask[(b << 11) + i];

  float qv[64];
  const float* qp = Q + (size_t)row * DP;
  #pragma unroll
  for (int i = 0; i < 16; ++i) {
    float4 v = *(const float4*)(qp + i * 4);
    qv[i * 4 + 0] = v.x; qv[i * 4 + 1] = v.y;
    qv[i * 4 + 2] = v.z; qv[i * 4 + 3] = v.w;
  }

  float min1 = FLT_MAX; int i1 = -1;
  float cval[16]; int cidx[16]; int cn = 0;

  for (int kt = 0; kt < 16; ++kt) {
    __syncthreads();
    #pragma unroll
    for (int i = 0; i < 8; ++i) {
      int e4 = t + (i << 8);            // float4 index 0..2047
      int d = e4 >> 5;                  // 0..63
      int k4 = (e4 & 31) << 2;          // 0..124
      *(float4*)&Ks[d][k4] =
          *(const float4*)(Kt + ((size_t)(bh << 6) + d) * SS + (kt << 7) + k4);
    }
    __syncthreads();

    for (int kk = 0; kk < 128; kk += 4) {
      float4 a = make_float4(0.f, 0.f, 0.f, 0.f);
      #pragma unroll
      for (int d = 0; d < 64; ++d) {
        float4 kv = *(const float4*)&Ks[d][kk];   // broadcast read
        a.x = fmaf(qv[d], kv.x, a.x);
        a.y = fmaf(qv[d], kv.y, a.y);
        a.z = fmaf(qv[d], kv.z, a.z);
        a.w = fmaf(qv[d], kv.w, a.w);
      }
      const int kb = (kt << 7) + kk;
      float sv[4] = {a.x, a.y, a.z, a.w};
      #pragma unroll
      for (int c = 0; c < 4; ++c) {
        const int k = kb + c;
        if (ms[k] == 0) {
          const float s = sv[c];
          if (s < min1) { min1 = s; i1 = k; }
          if (s < min1 + MARGIN) {          // candidate (superset-safe)
            if (cn == 16) {                 // compact vs current min
              int w = 0;
              for (int j = 0; j < 16; ++j)
                if (cval[j] < min1 + MARGIN) { cval[w] = cval[j]; cidx[w] = cidx[j]; ++w; }
              cn = w;
            }
            if (cn < 16) { cval[cn] = s; cidx[cn] = k; ++cn; }
            else {
              int mj = 0;
              for (int j = 1; j < 16; ++j) if (cval[j] > cval[mj]) mj = j;
              if (s < cval[mj]) { cval[mj] = s; cidx[mj] = k; }
            }
          }
        }
      }
    }
  }

  if (i1 < 0) i1 = 0;       // unreachable safety
  idx[row] = i1;

  int w = 0;
  const float thr = min1 + MARGIN;
  for (int j = 0; j < cn; ++j)
    if (cval[j] < thr) cidx[w++] = cidx[j];
  if (w >= 2) {
    int pos = atomicAdd(ambig_cnt, 1);
    ambig_rows[pos] = row;
    cand_cnt[row] = w;
    for (int j = 0; j < w; ++j) cand[row * 16 + j] = cidx[j];
  }
}

// ---------------------------------------------------------------------------
// Kernel 3: f64 refinement of ambiguous rows.  Recomputes Q-row and each
// candidate K-row directly from x and W with f64 accumulation (fp32 products
// are exact in f64), then picks the true argmin.  ~150 rows expected.
// ---------------------------------------------------------------------------
__global__ __launch_bounds__(64) void refine_kernel(
    const float* __restrict__ x, const float* __restrict__ Wq,
    const float* __restrict__ Wk,
    const int* __restrict__ ambig_rows, const int* __restrict__ ambig_cnt,
    const int* __restrict__ cand, const int* __restrict__ cand_cnt,
    int* __restrict__ idx)
{
  const int n = *ambig_cnt;
  const int lane = threadIdx.x;
  for (int it = blockIdx.x; it < n; it += gridDim.x) {
    const int row = ambig_rows[it];
    const int bh = row >> 11, q = row & 2047;
    const int b = bh >> 4, h = bh & 15;
    const int wc = (h << 6) + lane;
    const float* xq = x + ((size_t)(b << 11) + q) * DD;
    double qd = 0.0;
    for (int j = 0; j < DD; ++j)
      qd = fma((double)xq[j], (double)Wq[(size_t)j * DD + wc], qd);

    const int cnum = cand_cnt[row];
    double best = 1e300; int bi = 0x7fffffff;
    for (int c = 0; c < cnum; ++c) {
      const int k = cand[row * 16 + c];
      const float* xk = x + ((size_t)(b << 11) + k) * DD;
      double kd = 0.0;
      for (int j = 0; j < DD; ++j)
        kd = fma((double)xk[j], (double)Wk[(size_t)j * DD + wc], kd);
      double p = qd * kd;
      #pragma unroll
      for (int o = 32; o > 0; o >>= 1) p += __shfl_xor(p, o, 64);
      if (p < best || (p == best && k < bi)) { best = p; bi = k; }
    }
    if (lane == 0) idx[row] = bi;
  }
}

// ---------------------------------------------------------------------------
// Kernel 4: gather V rows per head (one-hot attention), project with W_o,
// add bias, apply inference BatchNorm.  8 output rows per block; W_o streams
// from L2 reused across the 8 rows.
// ---------------------------------------------------------------------------
__global__ __launch_bounds__(256) void out_kernel(
    const float* __restrict__ V, const int* __restrict__ idx,
    const float* __restrict__ Wo, const float* __restrict__ bo,
    const float* __restrict__ gamma, const float* __restrict__ beta,
    const float* __restrict__ mmean, const float* __restrict__ mvar,
    float* __restrict__ out)
{
  __shared__ float AO[8][1024];
  const int m0 = blockIdx.x << 3;
  const int b = m0 >> 11;
  const int s0 = m0 & 2047;
  const int t = threadIdx.x;

  for (int r = 0; r < 8; ++r) {
    const int srow = s0 + r;
    for (int i = t; i < DD; i += 256) {
      const int h = i >> 6, d = i & 63;
      const int k = idx[((b << 4) + h) * SS + srow];
      AO[r][i] = V[((size_t)((b << 4) + h) * SS + k) * DP + d];
    }
  }
  __syncthreads();

  const int e0 = t << 2;
  float4 acc[8];
  #pragma unroll
  for (int r = 0; r < 8; ++r) acc[r] = make_float4(0.f, 0.f, 0.f, 0.f);

  for (int i = 0; i < DD; ++i) {
    float4 w = *(const float4*)(Wo + (size_t)i * DD + e0);
    #pragma unroll
    for (int r = 0; r < 8; ++r) {
      const float a = AO[r][i];
      acc[r].x = fmaf(a, w.x, acc[r].x);
      acc[r].y = fmaf(a, w.y, acc[r].y);
      acc[r].z = fmaf(a, w.z, acc[r].z);
      acc[r].w = fmaf(a, w.w, acc[r].w);
    }
  }

  float4 bb = *(const float4*)(bo + e0);
  float4 gg = *(const float4*)(gamma + e0);
  float4 be = *(const float4*)(beta + e0);
  float4 mm = *(const float4*)(mmean + e0);
  float4 mv = *(const float4*)(mvar + e0);
  float scx = gg.x / sqrtf(mv.x + 1e-3f);
  float scy = gg.y / sqrtf(mv.y + 1e-3f);
  float scz = gg.z / sqrtf(mv.z + 1e-3f);
  float scw = gg.w / sqrtf(mv.w + 1e-3f);

  #pragma unroll
  for (int r = 0; r < 8; ++r) {
    float4 o;
    o.x = (acc[r].x + bb.x - mm.x) * scx + be.x;
    o.y = (acc[r].y + bb.y - mm.y) * scy + be.y;
    o.z = (acc[r].z + bb.z - mm.z) * scz + be.z;
    o.w = (acc[r].w + bb.w - mm.w) * scw + be.w;
    *(float4*)(out + (size_t)(m0 + r) * DD + e0) = o;
  }
}

// ---------------------------------------------------------------------------
extern "C" void kernel_launch(void* const* d_in, const int* in_sizes, int n_in,
                              void* d_out, int out_size, void* d_ws, size_t ws_size,
                              hipStream_t stream)
{
  const float* x  = (const float*)d_in[0];
  const int* mask = (const int*)d_in[1];
  const float* Wq = (const float*)d_in[2];
  const float* Wk = (const float*)d_in[3];
  const float* Wv = (const float*)d_in[4];
  const float* Wo = (const float*)d_in[5];
  const float* bo = (const float*)d_in[6];
  const float* ga = (const float*)d_in[7];
  const float* be = (const float*)d_in[8];
  const float* mm = (const float*)d_in[9];
  const float* mv = (const float*)d_in[10];
  float* out = (float*)d_out;

  char* ws = (char*)d_ws;
  float* Q    = (float*)(ws + 0);           // 32 MB  [B*H][S][64]
  float* Kt   = (float*)(ws + 33554432);    // 32 MB  [B*H][64][S]
  float* V    = (float*)(ws + 67108864);    // 32 MB  [B*H][S][64]
  int* idx    = (int*)(ws + 100663296);     // 0.5 MB
  int* ambr   = (int*)(ws + 101187584);     // 0.5 MB
  int* ambc   = (int*)(ws + 101711872);     // 4 B counter
  int* ccnt   = (int*)(ws + 101712128);     // 0.5 MB per-row cand count
  int* cnd    = (int*)(ws + 102236416);     // 8 MB cand idx [NROW][16]

  hipMemsetAsync(ambc, 0, 4, stream);
  proj_kernel<<<dim3(64, 8, 3), 256, 0, stream>>>(x, Wq, Wk, Wv, Q, Kt, V);
  filter_kernel<<<512, 256, 0, stream>>>(Q, Kt, mask, idx, ambr, ambc, cnd, ccnt);
  refine_kernel<<<256, 64, 0, stream>>>(x, Wq, Wk, ambr, ambc, cnd, ccnt, idx);
  out_kernel<<<1024, 256, 0, stream>>>(V, idx, Wo, bo, ga, be, mm, mv, out);
}

// Round 4
// 1655.153 us; speedup vs baseline: 1.4857x; 1.4857x over previous
//
#include <hip/hip_runtime.h>
#include <hip/hip_bf16.h>
#include <float.h>

#define BB 4
#define SS 2048
#define DD 1024
#define HH 16
#define DP 64
#define MARGIN_F 0.04f   /* ~8x worst-case split+packing error at |s|~16 */

typedef __attribute__((ext_vector_type(8))) short short8v;
typedef __attribute__((ext_vector_type(16))) float f32x16;

static __device__ __forceinline__ ushort f2bf(float f) {
  __hip_bfloat16 h = __float2bfloat16(f);
  return *reinterpret_cast<ushort*>(&h);
}
static __device__ __forceinline__ float bf2f(ushort u) {
  __hip_bfloat16 h;
  *reinterpret_cast<ushort*>(&h) = u;
  return __bfloat162float(h);
}

// ---------------------------------------------------------------------------
// Kernel 1: fp32 projection GEMM  C = x(8192x1024) @ W(1024x1024), z selects
// Wq/Wk/Wv.  Epilogue: z=0 -> Qhi/Qlo bf16 split, z=1 -> Khi/Klo bf16 split,
// z=2 -> V bf16.  All head-split row-major [bh][s][64].
// ---------------------------------------------------------------------------
__global__ __launch_bounds__(256) void proj_kernel(
    const float* __restrict__ x, const float* __restrict__ Wq,
    const float* __restrict__ Wk, const float* __restrict__ Wv,
    ushort* __restrict__ Qhi, ushort* __restrict__ Qlo,
    ushort* __restrict__ Khi, ushort* __restrict__ Klo,
    ushort* __restrict__ Vb)
{
  const int z = blockIdx.z;
  const float* __restrict__ W = (z == 0) ? Wq : (z == 1 ? Wk : Wv);
  __shared__ float As[16][132];
  __shared__ float Bs[16][132];
  const int row0 = blockIdx.x * 128;
  const int col0 = blockIdx.y * 128;
  const int tid = threadIdx.x;
  const int ty = tid >> 4, tx = tid & 15;

  float acc[8][8];
  #pragma unroll
  for (int i = 0; i < 8; ++i)
    #pragma unroll
    for (int j = 0; j < 8; ++j) acc[i][j] = 0.f;

  for (int t = 0; t < 64; ++t) {
    const int k0 = t * 16;
    #pragma unroll
    for (int i = 0; i < 2; ++i) {
      int e = tid + i * 256;
      int m = e >> 2;
      int k4 = (e & 3) << 2;
      float4 v = *(const float4*)(x + (size_t)(row0 + m) * DD + k0 + k4);
      As[k4 + 0][m] = v.x; As[k4 + 1][m] = v.y;
      As[k4 + 2][m] = v.z; As[k4 + 3][m] = v.w;
    }
    #pragma unroll
    for (int i = 0; i < 2; ++i) {
      int e = tid + i * 256;
      int k = e >> 5;
      int n4 = (e & 31) << 2;
      *(float4*)&Bs[k][n4] = *(const float4*)(W + (size_t)(k0 + k) * DD + col0 + n4);
    }
    __syncthreads();
    #pragma unroll
    for (int k = 0; k < 16; ++k) {
      float4 a0 = *(const float4*)&As[k][ty * 8];
      float4 a1 = *(const float4*)&As[k][ty * 8 + 4];
      float4 b0 = *(const float4*)&Bs[k][tx * 8];
      float4 b1 = *(const float4*)&Bs[k][tx * 8 + 4];
      float av[8] = {a0.x, a0.y, a0.z, a0.w, a1.x, a1.y, a1.z, a1.w};
      float bv[8] = {b0.x, b0.y, b0.z, b0.w, b1.x, b1.y, b1.z, b1.w};
      #pragma unroll
      for (int i = 0; i < 8; ++i)
        #pragma unroll
        for (int j = 0; j < 8; ++j) acc[i][j] = fmaf(av[i], bv[j], acc[i][j]);
    }
    __syncthreads();
  }

  #pragma unroll
  for (int i = 0; i < 8; ++i) {
    const int m = row0 + ty * 8 + i;
    const int b = m >> 11, s = m & 2047;
    const int n0 = col0 + tx * 8;
    const int h = n0 >> 6, d0 = n0 & 63;
    const size_t base = ((size_t)(b * HH + h) * SS + s) * DP + d0;
    if (z == 2) {
      short8v v8;
      #pragma unroll
      for (int j = 0; j < 8; ++j) v8[j] = (short)f2bf(acc[i][j]);
      *(short8v*)(Vb + base) = v8;
    } else {
      short8v h8, l8;
      #pragma unroll
      for (int j = 0; j < 8; ++j) {
        const float f = acc[i][j];
        const ushort hu = f2bf(f);
        h8[j] = (short)hu;
        l8[j] = (short)f2bf(f - bf2f(hu));
      }
      ushort* dh = (z == 0) ? Qhi : Khi;
      ushort* dl = (z == 0) ? Qlo : Klo;
      *(short8v*)(dh + base) = h8;
      *(short8v*)(dl + base) = l8;
    }
  }
}

// ---------------------------------------------------------------------------
// Kernel 2: per-batch mask scan -> compact key list, padded to x32 with
// duplicates of the first masked key.  Writes BOTH the real count (for
// validity masking in the filter) and the padded count.
// ---------------------------------------------------------------------------
__global__ __launch_bounds__(256) void scan_kernel(
    const int* __restrict__ mask, int* __restrict__ klist,
    int* __restrict__ cntpad, int* __restrict__ cntreal)
{
  __shared__ int part[256];
  __shared__ int tot;
  const int b = blockIdx.x, t = threadIdx.x;
  int loc[8]; int c = 0;
  #pragma unroll
  for (int j = 0; j < 8; ++j) {
    loc[j] = (mask[(b << 11) + t * 8 + j] == 0);
    c += loc[j];
  }
  part[t] = c;
  __syncthreads();
  if (t == 0) {
    int run = 0;
    for (int i = 0; i < 256; ++i) { int v = part[i]; part[i] = run; run += v; }
    tot = run;
  }
  __syncthreads();
  int off = part[t];
  #pragma unroll
  for (int j = 0; j < 8; ++j)
    if (loc[j]) klist[(b << 11) + off++] = t * 8 + j;
  __syncthreads();
  if (t == 0) {
    int n = tot;
    int first;
    if (n == 0) { klist[b << 11] = 0; n = 1; first = 0; }
    else first = klist[b << 11];
    int np = (n + 31) & ~31;
    for (int i = n; i < np; ++i) klist[(b << 11) + i] = first;
    cntpad[b] = np;
    cntreal[b] = n;
  }
}

// ---------------------------------------------------------------------------
// Kernel 3: MFMA masked-argmin filter.  Wave = one 32q tile; 3-pass bf16
// split QK^T (swapped: A=K rows via klist indirection, B=Q cols) into fp32
// acc; scores packed with 11-bit compact key index, streamed into per-lane
// top-6 via fmed3 chains.  Padded slots (global compact index >= nreal) are
// forced to +FLT_MAX so duplicates can never evict real candidates.
// ---------------------------------------------------------------------------
__global__ __launch_bounds__(256) void filter_kernel(
    const ushort* __restrict__ Qhi, const ushort* __restrict__ Qlo,
    const ushort* __restrict__ Khi, const ushort* __restrict__ Klo,
    const int* __restrict__ klist, const int* __restrict__ cntpad,
    const int* __restrict__ cntreal,
    int* __restrict__ idx, int* __restrict__ ambr, int* __restrict__ ambc,
    int* __restrict__ cand, int* __restrict__ ccnt)
{
  const int bh = blockIdx.x >> 4;
  const int b = bh >> 4;
  const int wid = threadIdx.x >> 6;
  const int l = threadIdx.x & 63;
  const int q0 = ((blockIdx.x & 15) << 7) + (wid << 5);
  const int half = l >> 5;
  const int lq = l & 31;
  const int* __restrict__ kl_b = klist + (b << 11);

  // Q fragments (B operand): lane -> q = q0+lq, k-dim = ds*16 + half*8 + e
  short8v qh[4], ql[4];
  {
    const size_t qrow = ((size_t)bh * SS + q0 + lq) * DP + half * 8;
    #pragma unroll
    for (int ds = 0; ds < 4; ++ds) {
      qh[ds] = *(const short8v*)(Qhi + qrow + ds * 16);
      ql[ds] = *(const short8v*)(Qlo + qrow + ds * 16);
    }
  }

  const int nreal = cntreal[b];
  const int nt = cntpad[b] >> 5;
  float m1 = FLT_MAX, m2 = FLT_MAX, m3 = FLT_MAX,
        m4 = FLT_MAX, m5 = FLT_MAX, m6 = FLT_MAX;
  uint kidx[16];
  #pragma unroll
  for (int r = 0; r < 16; ++r)
    kidx[r] = (uint)((r & 3) + ((r >> 2) << 3) + (half << 2));

  const size_t kbase = (size_t)bh * SS;
  for (int t = 0; t < nt; ++t) {
    const int kval = kl_b[(t << 5) + lq];
    const size_t krow = (kbase + kval) * DP + half * 8;
    f32x16 acc;
    #pragma unroll
    for (int r = 0; r < 16; ++r) acc[r] = 0.f;
    #pragma unroll
    for (int ds = 0; ds < 4; ++ds) {
      short8v kh = *(const short8v*)(Khi + krow + ds * 16);
      short8v kl = *(const short8v*)(Klo + krow + ds * 16);
      acc = __builtin_amdgcn_mfma_f32_32x32x16_bf16(kh, qh[ds], acc, 0, 0, 0);
      acc = __builtin_amdgcn_mfma_f32_32x32x16_bf16(kh, ql[ds], acc, 0, 0, 0);
      acc = __builtin_amdgcn_mfma_f32_32x32x16_bf16(kl, qh[ds], acc, 0, 0, 0);
    }
    const bool part = (t == nt - 1) && ((nreal & 31) != 0);
    #pragma unroll
    for (int r = 0; r < 16; ++r) {
      const uint pv = (__float_as_uint(acc[r]) & 0xFFFFF800u) | kidx[r];
      float v = __uint_as_float(pv);
      if (part && kidx[r] >= (uint)nreal) v = FLT_MAX;   // padded slot: never competes
      m6 = __builtin_amdgcn_fmed3f(v, m5, m6);
      m5 = __builtin_amdgcn_fmed3f(v, m4, m5);
      m4 = __builtin_amdgcn_fmed3f(v, m3, m4);
      m3 = __builtin_amdgcn_fmed3f(v, m2, m3);
      m2 = __builtin_amdgcn_fmed3f(v, m1, m2);
      m1 = fminf(v, m1);
      kidx[r] += 32;
    }
  }

  // merge the two 32-lane halves (each covered half the k rows)
  float om[6];
  om[0] = __shfl_xor(m1, 32, 64);
  om[1] = __shfl_xor(m2, 32, 64);
  om[2] = __shfl_xor(m3, 32, 64);
  om[3] = __shfl_xor(m4, 32, 64);
  om[4] = __shfl_xor(m5, 32, 64);
  om[5] = __shfl_xor(m6, 32, 64);
  #pragma unroll
  for (int j = 0; j < 6; ++j) {
    const float v = om[j];
    m6 = __builtin_amdgcn_fmed3f(v, m5, m6);
    m5 = __builtin_amdgcn_fmed3f(v, m4, m5);
    m4 = __builtin_amdgcn_fmed3f(v, m3, m4);
    m3 = __builtin_amdgcn_fmed3f(v, m2, m3);
    m2 = __builtin_amdgcn_fmed3f(v, m1, m2);
    m1 = fminf(v, m1);
  }

  if (half == 0) {
    const int row = bh * SS + q0 + lq;
    const uint u1 = __float_as_uint(m1);
    const int k1 = kl_b[u1 & 2047u];
    idx[row] = k1;
    const float v1 = __uint_as_float(u1 & 0xFFFFF800u);
    const uint us[5] = {__float_as_uint(m2), __float_as_uint(m3),
                        __float_as_uint(m4), __float_as_uint(m5),
                        __float_as_uint(m6)};
    const float v2 = __uint_as_float(us[0] & 0xFFFFF800u);
    if (v2 - v1 < MARGIN_F) {
      int c[6]; int n = 0;
      c[n++] = k1;
      #pragma unroll
      for (int j = 0; j < 5; ++j) {
        const float vj = __uint_as_float(us[j] & 0xFFFFF800u);
        if (vj - v1 < MARGIN_F) c[n++] = kl_b[us[j] & 2047u];
        else break;
      }
      const int pos = atomicAdd(ambc, 1);
      ambr[pos] = row;
      ccnt[row] = n;
      for (int j = 0; j < n; ++j) cand[row * 8 + j] = c[j];
    }
  }
}

// ---------------------------------------------------------------------------
// Kernel 4: f64 refinement of ambiguous rows (ground truth from x, W).
// 4-way unrolled accumulators break the dependent-FMA chain.
// ---------------------------------------------------------------------------
__global__ __launch_bounds__(64) void refine_kernel(
    const float* __restrict__ x, const float* __restrict__ Wq,
    const float* __restrict__ Wk,
    const int* __restrict__ ambig_rows, const int* __restrict__ ambig_cnt,
    const int* __restrict__ cand, const int* __restrict__ cand_cnt,
    int* __restrict__ idx)
{
  const int n = *ambig_cnt;
  const int lane = threadIdx.x;
  for (int it = blockIdx.x; it < n; it += gridDim.x) {
    const int row = ambig_rows[it];
    const int bh = row >> 11, q = row & 2047;
    const int b = bh >> 4, h = bh & 15;
    const int wc = (h << 6) + lane;
    const float* xq = x + ((size_t)(b << 11) + q) * DD;
    double a0 = 0.0, a1 = 0.0, a2 = 0.0, a3 = 0.0;
    for (int j = 0; j < DD; j += 4) {
      a0 = fma((double)xq[j + 0], (double)Wq[(size_t)(j + 0) * DD + wc], a0);
      a1 = fma((double)xq[j + 1], (double)Wq[(size_t)(j + 1) * DD + wc], a1);
      a2 = fma((double)xq[j + 2], (double)Wq[(size_t)(j + 2) * DD + wc], a2);
      a3 = fma((double)xq[j + 3], (double)Wq[(size_t)(j + 3) * DD + wc], a3);
    }
    const double qd = (a0 + a1) + (a2 + a3);

    const int cnum = cand_cnt[row];
    double best = 1e300; int bi = 0x7fffffff;
    for (int c = 0; c < cnum; ++c) {
      const int k = cand[row * 8 + c] & 2047;
      const float* xk = x + ((size_t)(b << 11) + k) * DD;
      double b0 = 0.0, b1 = 0.0, b2 = 0.0, b3 = 0.0;
      for (int j = 0; j < DD; j += 4) {
        b0 = fma((double)xk[j + 0], (double)Wk[(size_t)(j + 0) * DD + wc], b0);
        b1 = fma((double)xk[j + 1], (double)Wk[(size_t)(j + 1) * DD + wc], b1);
        b2 = fma((double)xk[j + 2], (double)Wk[(size_t)(j + 2) * DD + wc], b2);
        b3 = fma((double)xk[j + 3], (double)Wk[(size_t)(j + 3) * DD + wc], b3);
      }
      const double kd = (b0 + b1) + (b2 + b3);
      double p = qd * kd;
      #pragma unroll
      for (int o = 32; o > 0; o >>= 1) p += __shfl_xor(p, o, 64);
      if (p < best || (p == best && k < bi)) { best = p; bi = k; }
    }
    if (lane == 0) idx[row] = bi;
  }
}

// ---------------------------------------------------------------------------
// Kernel 5: gather V rows (one-hot attention), project with W_o, bias, BN.
// ---------------------------------------------------------------------------
__global__ __launch_bounds__(256) void out_kernel(
    const ushort* __restrict__ Vb, const int* __restrict__ idx,
    const float* __restrict__ Wo, const float* __restrict__ bo,
    const float* __restrict__ gamma, const float* __restrict__ beta,
    const float* __restrict__ mmean, const float* __restrict__ mvar,
    float* __restrict__ out)
{
  __shared__ float AO[8][1024];
  const int m0 = blockIdx.x << 3;
  const int b = m0 >> 11;
  const int s0 = m0 & 2047;
  const int t = threadIdx.x;

  for (int r = 0; r < 8; ++r) {
    const int srow = s0 + r;
    for (int i = t; i < DD; i += 256) {
      const int h = i >> 6, d = i & 63;
      const int k = idx[((b << 4) + h) * SS + srow];
      AO[r][i] = bf2f(Vb[((size_t)((b << 4) + h) * SS + k) * DP + d]);
    }
  }
  __syncthreads();

  const int e0 = t << 2;
  float4 acc[8];
  #pragma unroll
  for (int r = 0; r < 8; ++r) acc[r] = make_float4(0.f, 0.f, 0.f, 0.f);

  for (int i = 0; i < DD; ++i) {
    float4 w = *(const float4*)(Wo + (size_t)i * DD + e0);
    #pragma unroll
    for (int r = 0; r < 8; ++r) {
      const float a = AO[r][i];
      acc[r].x = fmaf(a, w.x, acc[r].x);
      acc[r].y = fmaf(a, w.y, acc[r].y);
      acc[r].z = fmaf(a, w.z, acc[r].z);
      acc[r].w = fmaf(a, w.w, acc[r].w);
    }
  }

  float4 bb = *(const float4*)(bo + e0);
  float4 gg = *(const float4*)(gamma + e0);
  float4 be = *(const float4*)(beta + e0);
  float4 mm = *(const float4*)(mmean + e0);
  float4 mv = *(const float4*)(mvar + e0);
  float scx = gg.x / sqrtf(mv.x + 1e-3f);
  float scy = gg.y / sqrtf(mv.y + 1e-3f);
  float scz = gg.z / sqrtf(mv.z + 1e-3f);
  float scw = gg.w / sqrtf(mv.w + 1e-3f);

  #pragma unroll
  for (int r = 0; r < 8; ++r) {
    float4 o;
    o.x = (acc[r].x + bb.x - mm.x) * scx + be.x;
    o.y = (acc[r].y + bb.y - mm.y) * scy + be.y;
    o.z = (acc[r].z + bb.z - mm.z) * scz + be.z;
    o.w = (acc[r].w + bb.w - mm.w) * scw + be.w;
    *(float4*)(out + (size_t)(m0 + r) * DD + e0) = o;
  }
}

// ---------------------------------------------------------------------------
extern "C" void kernel_launch(void* const* d_in, const int* in_sizes, int n_in,
                              void* d_out, int out_size, void* d_ws, size_t ws_size,
                              hipStream_t stream)
{
  const float* x  = (const float*)d_in[0];
  const int* mask = (const int*)d_in[1];
  const float* Wq = (const float*)d_in[2];
  const float* Wk = (const float*)d_in[3];
  const float* Wv = (const float*)d_in[4];
  const float* Wo = (const float*)d_in[5];
  const float* bo = (const float*)d_in[6];
  const float* ga = (const float*)d_in[7];
  const float* be = (const float*)d_in[8];
  const float* mm = (const float*)d_in[9];
  const float* mv = (const float*)d_in[10];
  float* out = (float*)d_out;

  char* ws = (char*)d_ws;
  ushort* Qhi  = (ushort*)(ws + 0);            // 16 MB
  ushort* Qlo  = (ushort*)(ws + 16777216);     // 16 MB
  ushort* Khi  = (ushort*)(ws + 33554432);     // 16 MB
  ushort* Klo  = (ushort*)(ws + 50331648);     // 16 MB
  ushort* Vb   = (ushort*)(ws + 67108864);     // 16 MB
  int* klist   = (int*)(ws + 83886080);        // 32 KB
  int* cntp    = (int*)(ws + 83918848);        // 128 B
  int* cntn    = (int*)(ws + 83918976);        // 128 B
  int* idx     = (int*)(ws + 83919104);        // 512 KB
  int* ambr    = (int*)(ws + 84443392);        // 512 KB
  int* ambc    = (int*)(ws + 84967680);        // 128 B
  int* ccnt    = (int*)(ws + 84967936);        // 512 KB
  int* cnd     = (int*)(ws + 85492224);        // 4 MB  (end ~89.7 MB)

  hipMemsetAsync(ambc, 0, 4, stream);
  proj_kernel<<<dim3(64, 8, 3), 256, 0, stream>>>(x, Wq, Wk, Wv, Qhi, Qlo, Khi, Klo, Vb);
  scan_kernel<<<BB, 256, 0, stream>>>(mask, klist, cntp, cntn);
  filter_kernel<<<1024, 256, 0, stream>>>(Qhi, Qlo, Khi, Klo, klist, cntp, cntn,
                                          idx, ambr, ambc, cnd, ccnt);
  refine_kernel<<<2048, 64, 0, stream>>>(x, Wq, Wk, ambr, ambc, cnd, ccnt, idx);
  out_kernel<<<1024, 256, 0, stream>>>(Vb, idx, Wo, bo, ga, be, mm, mv, out);
}

// Round 5
// 1012.107 us; speedup vs baseline: 2.4296x; 1.6354x over previous
//
#include <hip/hip_runtime.h>
#include <hip/hip_bf16.h>
#include <float.h>

#define BB 4
#define SS 2048
#define DD 1024
#define HH 16
#define DP 64
#define MARGIN_F 0.05f   /* covers 2x(score err ~6e-3 + packing ulp ~8e-3) with 1.8x headroom */

typedef __attribute__((ext_vector_type(8))) _Float16 half8v;
typedef __attribute__((ext_vector_type(16))) float f32x16;

// ---------------------------------------------------------------------------
// Prep 1: cast x (8192x1024 f32) -> fp16, same layout.
// ---------------------------------------------------------------------------
__global__ __launch_bounds__(256) void xcast_kernel(
    const float* __restrict__ x, _Float16* __restrict__ xh)
{
  const size_t e0 = ((size_t)blockIdx.x * 256 + threadIdx.x) * 8;
  float4 v0 = *(const float4*)(x + e0);
  float4 v1 = *(const float4*)(x + e0 + 4);
  half8v h;
  h[0] = (_Float16)v0.x; h[1] = (_Float16)v0.y;
  h[2] = (_Float16)v0.z; h[3] = (_Float16)v0.w;
  h[4] = (_Float16)v1.x; h[5] = (_Float16)v1.y;
  h[6] = (_Float16)v1.z; h[7] = (_Float16)v1.w;
  *(half8v*)(xh + e0) = h;
}

// ---------------------------------------------------------------------------
// Prep 2: transpose+cast W[k][n] f32 -> Wt[n][k] fp16 for Wq,Wk,Wv,Wo.
// ---------------------------------------------------------------------------
__global__ __launch_bounds__(256) void wtrans_kernel(
    const float* __restrict__ Wq, const float* __restrict__ Wk,
    const float* __restrict__ Wv, const float* __restrict__ Wo,
    _Float16* __restrict__ Wqt, _Float16* __restrict__ Wkt,
    _Float16* __restrict__ Wvt, _Float16* __restrict__ Wot)
{
  const int z = blockIdx.z;
  const float* __restrict__ src = (z == 0) ? Wq : (z == 1 ? Wk : (z == 2 ? Wv : Wo));
  _Float16* __restrict__ dst = (z == 0) ? Wqt : (z == 1 ? Wkt : (z == 2 ? Wvt : Wot));
  __shared__ float tile[64][65];
  const int k0 = blockIdx.x * 64, n0 = blockIdx.y * 64;
  const int c = threadIdx.x & 63, rb = threadIdx.x >> 6;
  #pragma unroll
  for (int i = 0; i < 16; ++i)
    tile[rb + 4 * i][c] = src[(size_t)(k0 + rb + 4 * i) * DD + n0 + c];
  __syncthreads();
  #pragma unroll
  for (int i = 0; i < 16; ++i) {
    const int n = n0 + rb + 4 * i;
    dst[(size_t)n * DD + k0 + c] = (_Float16)tile[c][rb + 4 * i];
  }
}

// ---------------------------------------------------------------------------
// Kernel: fp16 MFMA projection GEMM.  C = xh(8192x1024) . Wt(1024x1024)^T
// (Wt is [n][k]).  z selects Wq/Wk/Wv -> Qh/Kh/Vh [bh][s][64] fp16.
// No LDS: A/B fragments load straight from L1/L2 (k-contiguous 16B/lane).
// ---------------------------------------------------------------------------
__global__ __launch_bounds__(256) void proj_mfma(
    const _Float16* __restrict__ xh,
    const _Float16* __restrict__ Wqt, const _Float16* __restrict__ Wkt,
    const _Float16* __restrict__ Wvt,
    _Float16* __restrict__ Qh, _Float16* __restrict__ Kh,
    _Float16* __restrict__ Vh)
{
  const int z = blockIdx.z;
  const _Float16* __restrict__ Wt = (z == 0) ? Wqt : (z == 1 ? Wkt : Wvt);
  _Float16* __restrict__ dst = (z == 0) ? Qh : (z == 1 ? Kh : Vh);
  const int rows0 = blockIdx.x * 128, cols0 = blockIdx.y * 128;
  const int w = threadIdx.x >> 6, l = threadIdx.x & 63;
  const int lr = l & 31, hi8 = (l >> 5) * 8;

  const size_t arow = (size_t)(rows0 + w * 32 + lr) * DD + hi8;
  size_t brow[4];
  #pragma unroll
  for (int cf = 0; cf < 4; ++cf)
    brow[cf] = (size_t)(cols0 + cf * 32 + lr) * DD + hi8;

  f32x16 acc[4];
  #pragma unroll
  for (int cf = 0; cf < 4; ++cf)
    #pragma unroll
    for (int r = 0; r < 16; ++r) acc[cf][r] = 0.f;

  #pragma unroll 4
  for (int s = 0; s < 64; ++s) {
    half8v a = *(const half8v*)(xh + arow + s * 16);
    #pragma unroll
    for (int cf = 0; cf < 4; ++cf) {
      half8v bf = *(const half8v*)(Wt + brow[cf] + s * 16);
      acc[cf] = __builtin_amdgcn_mfma_f32_32x32x16_f16(a, bf, acc[cf], 0, 0, 0);
    }
  }

  const int m_base = rows0 + w * 32 + 4 * (l >> 5);
  #pragma unroll
  for (int cf = 0; cf < 4; ++cf) {
    const int n = cols0 + cf * 32 + lr;
    const int h = n >> 6, d = n & 63;
    #pragma unroll
    for (int r = 0; r < 16; ++r) {
      const int m = m_base + (r & 3) + 8 * (r >> 2);
      const int b = m >> 11, srow = m & 2047;
      dst[((size_t)(b * HH + h) * SS + srow) * DP + d] = (_Float16)acc[cf][r];
    }
  }
}

// ---------------------------------------------------------------------------
// Mask scan -> compact key list padded to x32 with duplicates of the first
// masked key; writes real count (for validity masking) and padded count.
// ---------------------------------------------------------------------------
__global__ __launch_bounds__(256) void scan_kernel(
    const int* __restrict__ mask, int* __restrict__ klist,
    int* __restrict__ cntpad, int* __restrict__ cntreal)
{
  __shared__ int part[256];
  __shared__ int tot;
  const int b = blockIdx.x, t = threadIdx.x;
  int loc[8]; int c = 0;
  #pragma unroll
  for (int j = 0; j < 8; ++j) {
    loc[j] = (mask[(b << 11) + t * 8 + j] == 0);
    c += loc[j];
  }
  part[t] = c;
  __syncthreads();
  if (t == 0) {
    int run = 0;
    for (int i = 0; i < 256; ++i) { int v = part[i]; part[i] = run; run += v; }
    tot = run;
  }
  __syncthreads();
  int off = part[t];
  #pragma unroll
  for (int j = 0; j < 8; ++j)
    if (loc[j]) klist[(b << 11) + off++] = t * 8 + j;
  __syncthreads();
  if (t == 0) {
    int n = tot;
    int first;
    if (n == 0) { klist[b << 11] = 0; n = 1; first = 0; }
    else first = klist[b << 11];
    int np = (n + 31) & ~31;
    for (int i = n; i < np; ++i) klist[(b << 11) + i] = first;
    cntpad[b] = np;
    cntreal[b] = n;
  }
}

// ---------------------------------------------------------------------------
// fp16 MFMA masked-argmin filter.  Wave = one 32q tile; single-pass fp16
// QK^T (A=K rows via klist, B=Q cols), scores packed with 11-bit compact key
// index -> per-lane top-6 via fmed3 chains.  Padded slots forced to +FLT_MAX.
// ---------------------------------------------------------------------------
__global__ __launch_bounds__(256) void filter_kernel(
    const _Float16* __restrict__ Qh, const _Float16* __restrict__ Kh,
    const int* __restrict__ klist, const int* __restrict__ cntpad,
    const int* __restrict__ cntreal,
    int* __restrict__ idx, int* __restrict__ ambr, int* __restrict__ ambc,
    int* __restrict__ cand, int* __restrict__ ccnt)
{
  const int bh = blockIdx.x >> 4;
  const int b = bh >> 4;
  const int wid = threadIdx.x >> 6;
  const int l = threadIdx.x & 63;
  const int q0 = ((blockIdx.x & 15) << 7) + (wid << 5);
  const int half = l >> 5;
  const int lq = l & 31;
  const int* __restrict__ kl_b = klist + (b << 11);

  half8v qf[4];
  {
    const size_t qrow = ((size_t)bh * SS + q0 + lq) * DP + half * 8;
    #pragma unroll
    for (int ds = 0; ds < 4; ++ds)
      qf[ds] = *(const half8v*)(Qh + qrow + ds * 16);
  }

  const int nreal = cntreal[b];
  const int nt = cntpad[b] >> 5;
  float m1 = FLT_MAX, m2 = FLT_MAX, m3 = FLT_MAX,
        m4 = FLT_MAX, m5 = FLT_MAX, m6 = FLT_MAX;
  uint kidx[16];
  #pragma unroll
  for (int r = 0; r < 16; ++r)
    kidx[r] = (uint)((r & 3) + ((r >> 2) << 3) + (half << 2));

  const size_t kbase = (size_t)bh * SS;
  for (int t = 0; t < nt; ++t) {
    const int kval = kl_b[(t << 5) + lq];
    const size_t krow = (kbase + kval) * DP + half * 8;
    f32x16 acc;
    #pragma unroll
    for (int r = 0; r < 16; ++r) acc[r] = 0.f;
    #pragma unroll
    for (int ds = 0; ds < 4; ++ds) {
      half8v kf = *(const half8v*)(Kh + krow + ds * 16);
      acc = __builtin_amdgcn_mfma_f32_32x32x16_f16(kf, qf[ds], acc, 0, 0, 0);
    }
    const bool part = (t == nt - 1) && ((nreal & 31) != 0);
    #pragma unroll
    for (int r = 0; r < 16; ++r) {
      const uint pv = (__float_as_uint(acc[r]) & 0xFFFFF800u) | kidx[r];
      float v = __uint_as_float(pv);
      if (part && kidx[r] >= (uint)nreal) v = FLT_MAX;   // padded: never competes
      m6 = __builtin_amdgcn_fmed3f(v, m5, m6);
      m5 = __builtin_amdgcn_fmed3f(v, m4, m5);
      m4 = __builtin_amdgcn_fmed3f(v, m3, m4);
      m3 = __builtin_amdgcn_fmed3f(v, m2, m3);
      m2 = __builtin_amdgcn_fmed3f(v, m1, m2);
      m1 = fminf(v, m1);
      kidx[r] += 32;
    }
  }

  float om[6];
  om[0] = __shfl_xor(m1, 32, 64);
  om[1] = __shfl_xor(m2, 32, 64);
  om[2] = __shfl_xor(m3, 32, 64);
  om[3] = __shfl_xor(m4, 32, 64);
  om[4] = __shfl_xor(m5, 32, 64);
  om[5] = __shfl_xor(m6, 32, 64);
  #pragma unroll
  for (int j = 0; j < 6; ++j) {
    const float v = om[j];
    m6 = __builtin_amdgcn_fmed3f(v, m5, m6);
    m5 = __builtin_amdgcn_fmed3f(v, m4, m5);
    m4 = __builtin_amdgcn_fmed3f(v, m3, m4);
    m3 = __builtin_amdgcn_fmed3f(v, m2, m3);
    m2 = __builtin_amdgcn_fmed3f(v, m1, m2);
    m1 = fminf(v, m1);
  }

  if (half == 0) {
    const int row = bh * SS + q0 + lq;
    const uint u1 = __float_as_uint(m1);
    const int k1 = kl_b[u1 & 2047u];
    idx[row] = k1;
    const float v1 = __uint_as_float(u1 & 0xFFFFF800u);
    const uint us[5] = {__float_as_uint(m2), __float_as_uint(m3),
                        __float_as_uint(m4), __float_as_uint(m5),
                        __float_as_uint(m6)};
    const float v2 = __uint_as_float(us[0] & 0xFFFFF800u);
    if (v2 - v1 < MARGIN_F) {
      int c[6]; int n = 0;
      c[n++] = k1;
      #pragma unroll
      for (int j = 0; j < 5; ++j) {
        const float vj = __uint_as_float(us[j] & 0xFFFFF800u);
        if (vj - v1 < MARGIN_F) c[n++] = kl_b[us[j] & 2047u];
        else break;
      }
      const int pos = atomicAdd(ambc, 1);
      ambr[pos] = row;
      ccnt[row] = n;
      for (int j = 0; j < n; ++j) cand[row * 8 + j] = c[j];
    }
  }
}

// ---------------------------------------------------------------------------
// f64 refinement of ambiguous rows (ground truth from x, W).
// ---------------------------------------------------------------------------
__global__ __launch_bounds__(64) void refine_kernel(
    const float* __restrict__ x, const float* __restrict__ Wq,
    const float* __restrict__ Wk,
    const int* __restrict__ ambig_rows, const int* __restrict__ ambig_cnt,
    const int* __restrict__ cand, const int* __restrict__ cand_cnt,
    int* __restrict__ idx)
{
  const int n = *ambig_cnt;
  const int lane = threadIdx.x;
  for (int it = blockIdx.x; it < n; it += gridDim.x) {
    const int row = ambig_rows[it];
    const int bh = row >> 11, q = row & 2047;
    const int b = bh >> 4, h = bh & 15;
    const int wc = (h << 6) + lane;
    const float* xq = x + ((size_t)(b << 11) + q) * DD;
    double a0 = 0.0, a1 = 0.0, a2 = 0.0, a3 = 0.0;
    for (int j = 0; j < DD; j += 4) {
      a0 = fma((double)xq[j + 0], (double)Wq[(size_t)(j + 0) * DD + wc], a0);
      a1 = fma((double)xq[j + 1], (double)Wq[(size_t)(j + 1) * DD + wc], a1);
      a2 = fma((double)xq[j + 2], (double)Wq[(size_t)(j + 2) * DD + wc], a2);
      a3 = fma((double)xq[j + 3], (double)Wq[(size_t)(j + 3) * DD + wc], a3);
    }
    const double qd = (a0 + a1) + (a2 + a3);

    const int cnum = cand_cnt[row];
    double best = 1e300; int bi = 0x7fffffff;
    for (int c = 0; c < cnum; ++c) {
      const int k = cand[row * 8 + c] & 2047;
      const float* xk = x + ((size_t)(b << 11) + k) * DD;
      double b0 = 0.0, b1 = 0.0, b2 = 0.0, b3 = 0.0;
      for (int j = 0; j < DD; j += 4) {
        b0 = fma((double)xk[j + 0], (double)Wk[(size_t)(j + 0) * DD + wc], b0);
        b1 = fma((double)xk[j + 1], (double)Wk[(size_t)(j + 1) * DD + wc], b1);
        b2 = fma((double)xk[j + 2], (double)Wk[(size_t)(j + 2) * DD + wc], b2);
        b3 = fma((double)xk[j + 3], (double)Wk[(size_t)(j + 3) * DD + wc], b3);
      }
      const double kd = (b0 + b1) + (b2 + b3);
      double p = qd * kd;
      #pragma unroll
      for (int o = 32; o > 0; o >>= 1) p += __shfl_xor(p, o, 64);
      if (p < best || (p == best && k < bi)) { best = p; bi = k; }
    }
    if (lane == 0) idx[row] = bi;
  }
}

// ---------------------------------------------------------------------------
// fp16 MFMA out-projection: A = gathered V rows (one-hot attention), B = Wot
// [n][k]; epilogue bias + inference BN, fp32 store.
// ---------------------------------------------------------------------------
__global__ __launch_bounds__(256) void out_mfma(
    const _Float16* __restrict__ Vh, const int* __restrict__ idx,
    const _Float16* __restrict__ Wot, const float* __restrict__ bo,
    const float* __restrict__ gamma, const float* __restrict__ beta,
    const float* __restrict__ mmean, const float* __restrict__ mvar,
    float* __restrict__ out)
{
  const int rows0 = blockIdx.x * 128, cols0 = blockIdx.y * 128;
  const int w = threadIdx.x >> 6, l = threadIdx.x & 63;
  const int lr = l & 31, hi8 = (l >> 5) * 8;
  const int m = rows0 + w * 32 + lr;      // this lane's A row
  const int b = m >> 11, srow = m & 2047;

  int vidx[16];
  #pragma unroll
  for (int h = 0; h < 16; ++h)
    vidx[h] = idx[(size_t)(b * HH + h) * SS + srow];

  size_t brow[4];
  #pragma unroll
  for (int cf = 0; cf < 4; ++cf)
    brow[cf] = (size_t)(cols0 + cf * 32 + lr) * DD + hi8;

  f32x16 acc[4];
  #pragma unroll
  for (int cf = 0; cf < 4; ++cf)
    #pragma unroll
    for (int r = 0; r < 16; ++r) acc[cf][r] = 0.f;

  #pragma unroll 4
  for (int s = 0; s < 64; ++s) {
    const int h = s >> 2;
    const int kk = (s & 3) * 16 + hi8;
    half8v a = *(const half8v*)(Vh + ((size_t)(b * HH + h) * SS + vidx[h]) * DP + kk);
    #pragma unroll
    for (int cf = 0; cf < 4; ++cf) {
      half8v bf = *(const half8v*)(Wot + brow[cf] + s * 16);
      acc[cf] = __builtin_amdgcn_mfma_f32_32x32x16_f16(a, bf, acc[cf], 0, 0, 0);
    }
  }

  const int m_base = rows0 + w * 32 + 4 * (l >> 5);
  #pragma unroll
  for (int cf = 0; cf < 4; ++cf) {
    const int n = cols0 + cf * 32 + lr;
    const float sc = gamma[n] * rsqrtf(mvar[n] + 1e-3f);
    const float ofs = (bo[n] - mmean[n]) * sc + beta[n];
    #pragma unroll
    for (int r = 0; r < 16; ++r) {
      const int mr = m_base + (r & 3) + 8 * (r >> 2);
      out[(size_t)mr * DD + n] = acc[cf][r] * sc + ofs;
    }
  }
}

// ---------------------------------------------------------------------------
extern "C" void kernel_launch(void* const* d_in, const int* in_sizes, int n_in,
                              void* d_out, int out_size, void* d_ws, size_t ws_size,
                              hipStream_t stream)
{
  const float* x  = (const float*)d_in[0];
  const int* mask = (const int*)d_in[1];
  const float* Wq = (const float*)d_in[2];
  const float* Wk = (const float*)d_in[3];
  const float* Wv = (const float*)d_in[4];
  const float* Wo = (const float*)d_in[5];
  const float* bo = (const float*)d_in[6];
  const float* ga = (const float*)d_in[7];
  const float* be = (const float*)d_in[8];
  const float* mm = (const float*)d_in[9];
  const float* mv = (const float*)d_in[10];
  float* out = (float*)d_out;

  char* ws = (char*)d_ws;
  _Float16* xh  = (_Float16*)(ws + 0);          // 16 MB
  _Float16* Qh  = (_Float16*)(ws + 16777216);   // 16 MB
  _Float16* Kh  = (_Float16*)(ws + 33554432);   // 16 MB
  _Float16* Vh  = (_Float16*)(ws + 50331648);   // 16 MB
  _Float16* Wqt = (_Float16*)(ws + 67108864);   // 2 MB
  _Float16* Wkt = (_Float16*)(ws + 69206016);   // 2 MB
  _Float16* Wvt = (_Float16*)(ws + 71303168);   // 2 MB
  _Float16* Wot = (_Float16*)(ws + 73400320);   // 2 MB
  int* klist    = (int*)(ws + 75497472);        // 32 KB
  int* cntp     = (int*)(ws + 75530240);        // 128 B
  int* cntn     = (int*)(ws + 75530368);        // 128 B
  int* idx      = (int*)(ws + 75530496);        // 512 KB
  int* ambr     = (int*)(ws + 76054784);        // 512 KB
  int* ambc     = (int*)(ws + 76579072);        // 128 B
  int* ccnt     = (int*)(ws + 76579200);        // 512 KB
  int* cnd      = (int*)(ws + 77103488);        // 4 MB (end ~81.3 MB)

  hipMemsetAsync(ambc, 0, 4, stream);
  xcast_kernel<<<4096, 256, 0, stream>>>(x, xh);
  wtrans_kernel<<<dim3(16, 16, 4), 256, 0, stream>>>(Wq, Wk, Wv, Wo,
                                                     Wqt, Wkt, Wvt, Wot);
  scan_kernel<<<BB, 256, 0, stream>>>(mask, klist, cntp, cntn);
  proj_mfma<<<dim3(64, 8, 3), 256, 0, stream>>>(xh, Wqt, Wkt, Wvt, Qh, Kh, Vh);
  filter_kernel<<<1024, 256, 0, stream>>>(Qh, Kh, klist, cntp, cntn,
                                          idx, ambr, ambc, cnd, ccnt);
  refine_kernel<<<2048, 64, 0, stream>>>(x, Wq, Wk, ambr, ambc, cnd, ccnt, idx);
  out_mfma<<<dim3(64, 8), 256, 0, stream>>>(Vh, idx, Wot, bo, ga, be, mm, mv, out);
}

// Round 7
// 777.846 us; speedup vs baseline: 3.1613x; 1.3012x over previous
//
#include <hip/hip_runtime.h>
#include <hip/hip_bf16.h>
#include <float.h>

#define BB 4
#define SS 2048
#define DD 1024
#define HH 16
#define DP 64
#define MARGIN_F 0.02f   /* >= 2*packing_ulp(3.9e-3) + 3-pass filter err, 2.5x headroom */
#define TIER2_TAU 1e-4   /* recon-gap below this -> ground-truth re-adjudication */

typedef __attribute__((ext_vector_type(8))) _Float16 half8v;
typedef __attribute__((ext_vector_type(16))) float f32x16;

// ---------------------------------------------------------------------------
// Prep: transpose W[k][n] f32 -> Wt[n][k] fp16 hi (+ fp16 lo residual for
// Wq,Wk).  z: 0=Wq(hi+lo) 1=Wk(hi+lo) 2=Wv(hi) 3=Wo(hi).
// ---------------------------------------------------------------------------
__global__ __launch_bounds__(256) void wtrans_kernel(
    const float* __restrict__ Wq, const float* __restrict__ Wk,
    const float* __restrict__ Wv, const float* __restrict__ Wo,
    _Float16* __restrict__ Wqh, _Float16* __restrict__ Wql,
    _Float16* __restrict__ Wkh, _Float16* __restrict__ Wkl,
    _Float16* __restrict__ Wvh, _Float16* __restrict__ Woh)
{
  const int z = blockIdx.z;
  const float* __restrict__ src = (z == 0) ? Wq : (z == 1 ? Wk : (z == 2 ? Wv : Wo));
  _Float16* __restrict__ dh = (z == 0) ? Wqh : (z == 1 ? Wkh : (z == 2 ? Wvh : Woh));
  _Float16* __restrict__ dl = (z == 0) ? Wql : Wkl;
  __shared__ float tile[64][65];
  const int k0 = blockIdx.x * 64, n0 = blockIdx.y * 64;
  const int c = threadIdx.x & 63, rb = threadIdx.x >> 6;
  #pragma unroll
  for (int i = 0; i < 16; ++i)
    tile[rb + 4 * i][c] = src[(size_t)(k0 + rb + 4 * i) * DD + n0 + c];
  __syncthreads();
  #pragma unroll
  for (int i = 0; i < 16; ++i) {
    const int n = n0 + rb + 4 * i;
    const float v = tile[c][rb + 4 * i];
    const _Float16 h = (_Float16)v;
    dh[(size_t)n * DD + k0 + c] = h;
    if (z < 2) dl[(size_t)n * DD + k0 + c] = (_Float16)(v - (float)h);
  }
}

// ---------------------------------------------------------------------------
// Projection GEMM, fp16 MFMA.  A = x rows (fp32, split to fp16 hi/lo on the
// fly), B = Wt[n][k] fp16 hi/lo.  z=0/1 (Q,K): 3-pass split -> fp32-accurate,
// stored as fp16 hi/lo pair.  z=2 (V): single pass, fp16 store.
// ---------------------------------------------------------------------------
__global__ __launch_bounds__(256) void proj_mfma(
    const float* __restrict__ x,
    const _Float16* __restrict__ Wqh, const _Float16* __restrict__ Wql,
    const _Float16* __restrict__ Wkh, const _Float16* __restrict__ Wkl,
    const _Float16* __restrict__ Wvh,
    _Float16* __restrict__ Qhi, _Float16* __restrict__ Qlo,
    _Float16* __restrict__ Khi, _Float16* __restrict__ Klo,
    _Float16* __restrict__ Vh)
{
  const int z = blockIdx.z;
  const _Float16* __restrict__ Wh = (z == 0) ? Wqh : (z == 1 ? Wkh : Wvh);
  const _Float16* __restrict__ Wl = (z == 0) ? Wql : Wkl;
  _Float16* __restrict__ dhi = (z == 0) ? Qhi : (z == 1 ? Khi : Vh);
  _Float16* __restrict__ dlo = (z == 0) ? Qlo : Klo;
  const int rows0 = blockIdx.x * 128, cols0 = blockIdx.y * 128;
  const int w = threadIdx.x >> 6, l = threadIdx.x & 63;
  const int lr = l & 31, hi8 = (l >> 5) * 8;

  const size_t arow = (size_t)(rows0 + w * 32 + lr) * DD + hi8;
  size_t brow[4];
  #pragma unroll
  for (int cf = 0; cf < 4; ++cf)
    brow[cf] = (size_t)(cols0 + cf * 32 + lr) * DD + hi8;

  f32x16 acc[4];
  #pragma unroll
  for (int cf = 0; cf < 4; ++cf)
    #pragma unroll
    for (int r = 0; r < 16; ++r) acc[cf][r] = 0.f;

  #pragma unroll 2
  for (int s = 0; s < 64; ++s) {
    const float4 v0 = *(const float4*)(x + arow + s * 16);
    const float4 v1 = *(const float4*)(x + arow + s * 16 + 4);
    const float xv[8] = {v0.x, v0.y, v0.z, v0.w, v1.x, v1.y, v1.z, v1.w};
    half8v ah, al;
    #pragma unroll
    for (int j = 0; j < 8; ++j) {
      ah[j] = (_Float16)xv[j];
      al[j] = (_Float16)(xv[j] - (float)ah[j]);
    }
    #pragma unroll
    for (int cf = 0; cf < 4; ++cf) {
      const half8v bh = *(const half8v*)(Wh + brow[cf] + s * 16);
      acc[cf] = __builtin_amdgcn_mfma_f32_32x32x16_f16(ah, bh, acc[cf], 0, 0, 0);
      if (z < 2) {
        const half8v bl = *(const half8v*)(Wl + brow[cf] + s * 16);
        acc[cf] = __builtin_amdgcn_mfma_f32_32x32x16_f16(al, bh, acc[cf], 0, 0, 0);
        acc[cf] = __builtin_amdgcn_mfma_f32_32x32x16_f16(ah, bl, acc[cf], 0, 0, 0);
      }
    }
  }

  const int m_base = rows0 + w * 32 + 4 * (l >> 5);
  #pragma unroll
  for (int cf = 0; cf < 4; ++cf) {
    const int n = cols0 + cf * 32 + lr;
    const int h = n >> 6, d = n & 63;
    #pragma unroll
    for (int r = 0; r < 16; ++r) {
      const int m = m_base + (r & 3) + 8 * (r >> 2);
      const int b = m >> 11, srow = m & 2047;
      const size_t o = ((size_t)(b * HH + h) * SS + srow) * DP + d;
      const float a = acc[cf][r];
      const _Float16 h16 = (_Float16)a;
      dhi[o] = h16;
      if (z < 2) dlo[o] = (_Float16)(a - (float)h16);
    }
  }
}

// ---------------------------------------------------------------------------
// Mask scan -> compact key list padded to x32 with duplicates of the first
// masked key; writes real count (for validity masking) and padded count.
// ---------------------------------------------------------------------------
__global__ __launch_bounds__(256) void scan_kernel(
    const int* __restrict__ mask, int* __restrict__ klist,
    int* __restrict__ cntpad, int* __restrict__ cntreal)
{
  __shared__ int part[256];
  __shared__ int tot;
  const int b = blockIdx.x, t = threadIdx.x;
  int loc[8]; int c = 0;
  #pragma unroll
  for (int j = 0; j < 8; ++j) {
    loc[j] = (mask[(b << 11) + t * 8 + j] == 0);
    c += loc[j];
  }
  part[t] = c;
  __syncthreads();
  if (t == 0) {
    int run = 0;
    for (int i = 0; i < 256; ++i) { int v = part[i]; part[i] = run; run += v; }
    tot = run;
  }
  __syncthreads();
  int off = part[t];
  #pragma unroll
  for (int j = 0; j < 8; ++j)
    if (loc[j]) klist[(b << 11) + off++] = t * 8 + j;
  __syncthreads();
  if (t == 0) {
    int n = tot;
    int first;
    if (n == 0) { klist[b << 11] = 0; n = 1; first = 0; }
    else first = klist[b << 11];
    int np = (n + 31) & ~31;
    for (int i = n; i < np; ++i) klist[(b << 11) + i] = first;
    cntpad[b] = np;
    cntreal[b] = n;
  }
}

// ---------------------------------------------------------------------------
// MFMA masked-argmin filter, 3-pass fp16 hi/lo (score err ~1e-5).  Wave = one
// 32q tile; A=K rows via klist, B=Q cols; scores packed with 11-bit compact
// key index -> per-lane top-6 via fmed3.  Padded slots forced to +FLT_MAX.
// ---------------------------------------------------------------------------
__global__ __launch_bounds__(256) void filter_kernel(
    const _Float16* __restrict__ Qhi, const _Float16* __restrict__ Qlo,
    const _Float16* __restrict__ Khi, const _Float16* __restrict__ Klo,
    const int* __restrict__ klist, const int* __restrict__ cntpad,
    const int* __restrict__ cntreal,
    int* __restrict__ idx, int* __restrict__ ambr, int* __restrict__ ambc,
    int* __restrict__ cand, int* __restrict__ ccnt)
{
  const int bh = blockIdx.x >> 4;
  const int b = bh >> 4;
  const int wid = threadIdx.x >> 6;
  const int l = threadIdx.x & 63;
  const int q0 = ((blockIdx.x & 15) << 7) + (wid << 5);
  const int half = l >> 5;
  const int lq = l & 31;
  const int* __restrict__ kl_b = klist + (b << 11);

  half8v qh[4], ql[4];
  {
    const size_t qrow = ((size_t)bh * SS + q0 + lq) * DP + half * 8;
    #pragma unroll
    for (int ds = 0; ds < 4; ++ds) {
      qh[ds] = *(const half8v*)(Qhi + qrow + ds * 16);
      ql[ds] = *(const half8v*)(Qlo + qrow + ds * 16);
    }
  }

  const int nreal = cntreal[b];
  const int nt = cntpad[b] >> 5;
  float m1 = FLT_MAX, m2 = FLT_MAX, m3 = FLT_MAX,
        m4 = FLT_MAX, m5 = FLT_MAX, m6 = FLT_MAX;
  uint kidx[16];
  #pragma unroll
  for (int r = 0; r < 16; ++r)
    kidx[r] = (uint)((r & 3) + ((r >> 2) << 3) + (half << 2));

  const size_t kbase = (size_t)bh * SS;
  for (int t = 0; t < nt; ++t) {
    const int kval = kl_b[(t << 5) + lq];
    const size_t krow = (kbase + kval) * DP + half * 8;
    f32x16 acc;
    #pragma unroll
    for (int r = 0; r < 16; ++r) acc[r] = 0.f;
    #pragma unroll
    for (int ds = 0; ds < 4; ++ds) {
      const half8v kh = *(const half8v*)(Khi + krow + ds * 16);
      const half8v kl = *(const half8v*)(Klo + krow + ds * 16);
      acc = __builtin_amdgcn_mfma_f32_32x32x16_f16(kh, qh[ds], acc, 0, 0, 0);
      acc = __builtin_amdgcn_mfma_f32_32x32x16_f16(kh, ql[ds], acc, 0, 0, 0);
      acc = __builtin_amdgcn_mfma_f32_32x32x16_f16(kl, qh[ds], acc, 0, 0, 0);
    }
    const bool part = (t == nt - 1) && ((nreal & 31) != 0);
    #pragma unroll
    for (int r = 0; r < 16; ++r) {
      const uint pv = (__float_as_uint(acc[r]) & 0xFFFFF800u) | kidx[r];
      float v = __uint_as_float(pv);
      if (part && kidx[r] >= (uint)nreal) v = FLT_MAX;   // padded: never competes
      m6 = __builtin_amdgcn_fmed3f(v, m5, m6);
      m5 = __builtin_amdgcn_fmed3f(v, m4, m5);
      m4 = __builtin_amdgcn_fmed3f(v, m3, m4);
      m3 = __builtin_amdgcn_fmed3f(v, m2, m3);
      m2 = __builtin_amdgcn_fmed3f(v, m1, m2);
      m1 = fminf(v, m1);
      kidx[r] += 32;
    }
  }

  float om[6];
  om[0] = __shfl_xor(m1, 32, 64);
  om[1] = __shfl_xor(m2, 32, 64);
  om[2] = __shfl_xor(m3, 32, 64);
  om[3] = __shfl_xor(m4, 32, 64);
  om[4] = __shfl_xor(m5, 32, 64);
  om[5] = __shfl_xor(m6, 32, 64);
  #pragma unroll
  for (int j = 0; j < 6; ++j) {
    const float v = om[j];
    m6 = __builtin_amdgcn_fmed3f(v, m5, m6);
    m5 = __builtin_amdgcn_fmed3f(v, m4, m5);
    m4 = __builtin_amdgcn_fmed3f(v, m3, m4);
    m3 = __builtin_amdgcn_fmed3f(v, m2, m3);
    m2 = __builtin_amdgcn_fmed3f(v, m1, m2);
    m1 = fminf(v, m1);
  }

  if (half == 0) {
    const int row = bh * SS + q0 + lq;
    const uint u1 = __float_as_uint(m1);
    const int k1 = kl_b[u1 & 2047u];
    idx[row] = k1;
    const float v1 = __uint_as_float(u1 & 0xFFFFF800u);
    const uint us[5] = {__float_as_uint(m2), __float_as_uint(m3),
                        __float_as_uint(m4), __float_as_uint(m5),
                        __float_as_uint(m6)};
    const float v2 = __uint_as_float(us[0] & 0xFFFFF800u);
    if (v2 - v1 < MARGIN_F) {
      int c[6]; int n = 0;
      c[n++] = k1;
      #pragma unroll
      for (int j = 0; j < 5; ++j) {
        const float vj = __uint_as_float(us[j] & 0xFFFFF800u);
        if (vj - v1 < MARGIN_F) c[n++] = kl_b[us[j] & 2047u];
        else break;
      }
      const int pos = atomicAdd(ambc, 1);
      ambr[pos] = row;
      ccnt[row] = n;
      for (int j = 0; j < n; ++j) cand[row * 8 + j] = c[j];
    }
  }
}

// ---------------------------------------------------------------------------
// Two-tier refine.  Tier 1: f64 scores from reconstructed fp16 hi/lo Q,K
// (cache-resident, ~1e-6 of our fp32 proj).  If the reconstructed top-2 gap
// < TIER2_TAU, tier 2 re-adjudicates ALL candidates with f64 ground truth
// from x,W columns (the referee that passed rounds 1/4/5).
// ---------------------------------------------------------------------------
__global__ __launch_bounds__(64) void refine_kernel(
    const _Float16* __restrict__ Qhi, const _Float16* __restrict__ Qlo,
    const _Float16* __restrict__ Khi, const _Float16* __restrict__ Klo,
    const float* __restrict__ x, const float* __restrict__ Wq,
    const float* __restrict__ Wk,
    const int* __restrict__ ambr, const int* __restrict__ ambc,
    const int* __restrict__ cand, const int* __restrict__ ccnt,
    int* __restrict__ idx)
{
  const int n = *ambc;
  const int lane = threadIdx.x;
  for (int it = blockIdx.x; it < n; it += gridDim.x) {
    const int row = ambr[it];
    const int bh = row >> 11;
    const int cnum = ccnt[row];

    // ---- tier 1: reconstructed-score ranking ----
    const size_t qb = (size_t)row * DP;
    const double q = (double)(float)Qhi[qb + lane] + (double)(float)Qlo[qb + lane];
    double best = 1e300, best2 = 1e300; int bi = 0x7fffffff;
    for (int c = 0; c < cnum; ++c) {
      const int k = cand[row * 8 + c] & 2047;
      const size_t kb = ((size_t)bh * SS + k) * DP;
      const double kv = (double)(float)Khi[kb + lane] + (double)(float)Klo[kb + lane];
      double p = q * kv;
      #pragma unroll
      for (int o = 32; o > 0; o >>= 1) p += __shfl_xor(p, o, 64);
      if (p < best) { best2 = best; best = p; bi = k; }
      else if (p < best2) best2 = p;
    }

    // ---- tier 2: ground truth from x,W when recon gap is too small ----
    if (best2 - best < TIER2_TAU) {
      const int qq = row & 2047;
      const int b = bh >> 4, h = bh & 15;
      const int wc = (h << 6) + lane;
      const float* xq = x + ((size_t)(b << 11) + qq) * DD;
      double a0 = 0.0, a1 = 0.0, a2 = 0.0, a3 = 0.0;
      for (int j = 0; j < DD; j += 4) {
        a0 = fma((double)xq[j + 0], (double)Wq[(size_t)(j + 0) * DD + wc], a0);
        a1 = fma((double)xq[j + 1], (double)Wq[(size_t)(j + 1) * DD + wc], a1);
        a2 = fma((double)xq[j + 2], (double)Wq[(size_t)(j + 2) * DD + wc], a2);
        a3 = fma((double)xq[j + 3], (double)Wq[(size_t)(j + 3) * DD + wc], a3);
      }
      const double qd = (a0 + a1) + (a2 + a3);
      best = 1e300; bi = 0x7fffffff;
      for (int c = 0; c < cnum; ++c) {
        const int k = cand[row * 8 + c] & 2047;
        const float* xk = x + ((size_t)(b << 11) + k) * DD;
        double b0 = 0.0, b1 = 0.0, b2 = 0.0, b3 = 0.0;
        for (int j = 0; j < DD; j += 4) {
          b0 = fma((double)xk[j + 0], (double)Wk[(size_t)(j + 0) * DD + wc], b0);
          b1 = fma((double)xk[j + 1], (double)Wk[(size_t)(j + 1) * DD + wc], b1);
          b2 = fma((double)xk[j + 2], (double)Wk[(size_t)(j + 2) * DD + wc], b2);
          b3 = fma((double)xk[j + 3], (double)Wk[(size_t)(j + 3) * DD + wc], b3);
        }
        const double kd = (b0 + b1) + (b2 + b3);
        double p = qd * kd;
        #pragma unroll
        for (int o = 32; o > 0; o >>= 1) p += __shfl_xor(p, o, 64);
        if (p < best || (p == best && k < bi)) { best = p; bi = k; }
      }
    }
    if (lane == 0) idx[row] = bi;
  }
}

// ---------------------------------------------------------------------------
// fp16 MFMA out-projection: A = gathered V rows (one-hot attention), B = Woh
// [n][k]; epilogue bias + inference BN, fp32 store.
// ---------------------------------------------------------------------------
__global__ __launch_bounds__(256) void out_mfma(
    const _Float16* __restrict__ Vh, const int* __restrict__ idx,
    const _Float16* __restrict__ Woh, const float* __restrict__ bo,
    const float* __restrict__ gamma, const float* __restrict__ beta,
    const float* __restrict__ mmean, const float* __restrict__ mvar,
    float* __restrict__ out)
{
  const int rows0 = blockIdx.x * 128, cols0 = blockIdx.y * 128;
  const int w = threadIdx.x >> 6, l = threadIdx.x & 63;
  const int lr = l & 31, hi8 = (l >> 5) * 8;
  const int m = rows0 + w * 32 + lr;
  const int b = m >> 11, srow = m & 2047;

  int vidx[16];
  #pragma unroll
  for (int h = 0; h < 16; ++h)
    vidx[h] = idx[(size_t)(b * HH + h) * SS + srow];

  size_t brow[4];
  #pragma unroll
  for (int cf = 0; cf < 4; ++cf)
    brow[cf] = (size_t)(cols0 + cf * 32 + lr) * DD + hi8;

  f32x16 acc[4];
  #pragma unroll
  for (int cf = 0; cf < 4; ++cf)
    #pragma unroll
    for (int r = 0; r < 16; ++r) acc[cf][r] = 0.f;

  #pragma unroll 4
  for (int s = 0; s < 64; ++s) {
    const int h = s >> 2;
    const int kk = (s & 3) * 16 + hi8;
    half8v a = *(const half8v*)(Vh + ((size_t)(b * HH + h) * SS + vidx[h]) * DP + kk);
    #pragma unroll
    for (int cf = 0; cf < 4; ++cf) {
      half8v bf = *(const half8v*)(Woh + brow[cf] + s * 16);
      acc[cf] = __builtin_amdgcn_mfma_f32_32x32x16_f16(a, bf, acc[cf], 0, 0, 0);
    }
  }

  const int m_base = rows0 + w * 32 + 4 * (l >> 5);
  #pragma unroll
  for (int cf = 0; cf < 4; ++cf) {
    const int n = cols0 + cf * 32 + lr;
    const float sc = gamma[n] * rsqrtf(mvar[n] + 1e-3f);
    const float ofs = (bo[n] - mmean[n]) * sc + beta[n];
    #pragma unroll
    for (int r = 0; r < 16; ++r) {
      const int mr = m_base + (r & 3) + 8 * (r >> 2);
      out[(size_t)mr * DD + n] = acc[cf][r] * sc + ofs;
    }
  }
}

// ---------------------------------------------------------------------------
extern "C" void kernel_launch(void* const* d_in, const int* in_sizes, int n_in,
                              void* d_out, int out_size, void* d_ws, size_t ws_size,
                              hipStream_t stream)
{
  const float* x  = (const float*)d_in[0];
  const int* mask = (const int*)d_in[1];
  const float* Wq = (const float*)d_in[2];
  const float* Wk = (const float*)d_in[3];
  const float* Wv = (const float*)d_in[4];
  const float* Wo = (const float*)d_in[5];
  const float* bo = (const float*)d_in[6];
  const float* ga = (const float*)d_in[7];
  const float* be = (const float*)d_in[8];
  const float* mm = (const float*)d_in[9];
  const float* mv = (const float*)d_in[10];
  float* out = (float*)d_out;

  char* ws = (char*)d_ws;
  _Float16* Qhi = (_Float16*)(ws + 0);          // 16 MB
  _Float16* Qlo = (_Float16*)(ws + 16777216);   // 16 MB
  _Float16* Khi = (_Float16*)(ws + 33554432);   // 16 MB
  _Float16* Klo = (_Float16*)(ws + 50331648);   // 16 MB
  _Float16* Vh  = (_Float16*)(ws + 67108864);   // 16 MB
  _Float16* Wqh = (_Float16*)(ws + 83886080);   // 2 MB
  _Float16* Wql = (_Float16*)(ws + 85983232);   // 2 MB
  _Float16* Wkh = (_Float16*)(ws + 88080384);   // 2 MB
  _Float16* Wkl = (_Float16*)(ws + 90177536);   // 2 MB
  _Float16* Wvh = (_Float16*)(ws + 92274688);   // 2 MB
  _Float16* Woh = (_Float16*)(ws + 94371840);   // 2 MB
  int* klist    = (int*)(ws + 96468992);        // 32 KB
  int* cntp     = (int*)(ws + 96501760);        // 128 B
  int* cntn     = (int*)(ws + 96501888);        // 128 B
  int* idx      = (int*)(ws + 96502016);        // 512 KB
  int* ambr     = (int*)(ws + 97026304);        // 512 KB
  int* ambc     = (int*)(ws + 97550592);        // 128 B
  int* ccnt     = (int*)(ws + 97550720);        // 512 KB
  int* cnd      = (int*)(ws + 98075008);        // 4 MB (end ~97.5 MB)

  hipMemsetAsync(ambc, 0, 4, stream);
  wtrans_kernel<<<dim3(16, 16, 4), 256, 0, stream>>>(Wq, Wk, Wv, Wo,
                                                     Wqh, Wql, Wkh, Wkl, Wvh, Woh);
  scan_kernel<<<BB, 256, 0, stream>>>(mask, klist, cntp, cntn);
  proj_mfma<<<dim3(64, 8, 3), 256, 0, stream>>>(x, Wqh, Wql, Wkh, Wkl, Wvh,
                                                Qhi, Qlo, Khi, Klo, Vh);
  filter_kernel<<<1024, 256, 0, stream>>>(Qhi, Qlo, Khi, Klo, klist, cntp, cntn,
                                          idx, ambr, ambc, cnd, ccnt);
  refine_kernel<<<2048, 64, 0, stream>>>(Qhi, Qlo, Khi, Klo, x, Wq, Wk,
                                         ambr, ambc, cnd, ccnt, idx);
  out_mfma<<<dim3(64, 8), 256, 0, stream>>>(Vh, idx, Woh, bo, ga, be, mm, mv, out);
}

// Round 8
// 548.917 us; speedup vs baseline: 4.4798x; 1.4171x over previous
//
#include <hip/hip_runtime.h>
#include <hip/hip_bf16.h>
#include <float.h>

#define BB 4
#define SS 2048
#define DD 1024
#define HH 16
#define DP 64
#define BKS 32
#define MARGIN_F 0.02f   /* >= 2*packing_ulp(3.9e-3) + 3-pass filter err, 2.5x headroom */
#define TIER2_TAU 1e-4   /* recon-gap below this -> ground-truth re-adjudication */

typedef __attribute__((ext_vector_type(8))) _Float16 half8v;
typedef __attribute__((ext_vector_type(16))) float f32x16;

typedef __attribute__((address_space(3))) void lds_void;
typedef const __attribute__((address_space(1))) void gbl_void;
static __device__ __forceinline__ void gload16(const void* g, void* l) {
  __builtin_amdgcn_global_load_lds((gbl_void*)g, (lds_void*)l, 16, 0, 0);
}

// ---------------------------------------------------------------------------
// Prep: transpose W[k][n] f32 -> Wt[n][k] fp16 hi (+ fp16 lo residual for
// Wq,Wk).  z: 0=Wq(hi+lo) 1=Wk(hi+lo) 2=Wv(hi) 3=Wo(hi).
// ---------------------------------------------------------------------------
__global__ __launch_bounds__(256) void wtrans_kernel(
    const float* __restrict__ Wq, const float* __restrict__ Wk,
    const float* __restrict__ Wv, const float* __restrict__ Wo,
    _Float16* __restrict__ Wqh, _Float16* __restrict__ Wql,
    _Float16* __restrict__ Wkh, _Float16* __restrict__ Wkl,
    _Float16* __restrict__ Wvh, _Float16* __restrict__ Woh)
{
  const int z = blockIdx.z;
  const float* __restrict__ src = (z == 0) ? Wq : (z == 1 ? Wk : (z == 2 ? Wv : Wo));
  _Float16* __restrict__ dh = (z == 0) ? Wqh : (z == 1 ? Wkh : (z == 2 ? Wvh : Woh));
  _Float16* __restrict__ dl = (z == 0) ? Wql : Wkl;
  __shared__ float tile[64][65];
  const int k0 = blockIdx.x * 64, n0 = blockIdx.y * 64;
  const int c = threadIdx.x & 63, rb = threadIdx.x >> 6;
  #pragma unroll
  for (int i = 0; i < 16; ++i)
    tile[rb + 4 * i][c] = src[(size_t)(k0 + rb + 4 * i) * DD + n0 + c];
  __syncthreads();
  #pragma unroll
  for (int i = 0; i < 16; ++i) {
    const int n = n0 + rb + 4 * i;
    const float v = tile[c][rb + 4 * i];
    const _Float16 h = (_Float16)v;
    dh[(size_t)n * DD + k0 + c] = h;
    if (z < 2) dl[(size_t)n * DD + k0 + c] = (_Float16)(v - (float)h);
  }
}

// ---------------------------------------------------------------------------
// LDS-staged fp16 MFMA projection GEMM (m97-class structure).
// A = x (fp32, split hi/lo on the fly, reg->ds_write staging, swizzled).
// B = Wt[n][k] fp16 hi/lo via global_load_lds (linear dest, inverse-swizzled
// global source; read side applies the same XOR -> ~2-way conflicts).
// z=0/1 (Q,K): 3-pass split, fp16 hi/lo store.  z=2 (V): 1-pass, fp16 store.
// Tile 128x128, BK=32, 4 waves 2x2 (64x64 each), acc[2][2] f32x16.
// ---------------------------------------------------------------------------
__global__ __launch_bounds__(256) void proj_mfma(
    const float* __restrict__ x,
    const _Float16* __restrict__ Wqh, const _Float16* __restrict__ Wql,
    const _Float16* __restrict__ Wkh, const _Float16* __restrict__ Wkl,
    const _Float16* __restrict__ Wvh,
    _Float16* __restrict__ Qhi, _Float16* __restrict__ Qlo,
    _Float16* __restrict__ Khi, _Float16* __restrict__ Klo,
    _Float16* __restrict__ Vh)
{
  const int z = blockIdx.z;
  const bool split = (z < 2);
  const _Float16* __restrict__ Wh = (z == 0) ? Wqh : (z == 1 ? Wkh : Wvh);
  const _Float16* __restrict__ Wl = (z == 0) ? Wql : Wkl;
  _Float16* __restrict__ dhi = (z == 0) ? Qhi : (z == 1 ? Khi : Vh);
  _Float16* __restrict__ dlo = (z == 0) ? Qlo : Klo;

  __shared__ _Float16 Asm[8192];   // 16 KB: 128 rows x 8 slots x 8 fp16
  __shared__ _Float16 Bsm[8192];   // 16 KB

  const int rows0 = blockIdx.x * 128, cols0 = blockIdx.y * 128;
  const int t = threadIdx.x;
  const int wid = t >> 6, l = t & 63;
  const int warpR = wid >> 1, warpC = wid & 1;
  const int lr = l & 31, lh = l >> 5;

  f32x16 acc[2][2];
  #pragma unroll
  for (int i = 0; i < 2; ++i)
    #pragma unroll
    for (int j = 0; j < 2; ++j)
      #pragma unroll
      for (int r = 0; r < 16; ++r) acc[i][j][r] = 0.f;

  // ---- A staging constants (reg->ds_write): thread t -> row t>>1, 16 k's
  const int arow = t >> 1;
  const int kc0 = (t & 1) * 2;                 // first 8-chunk index (0 or 2)
  const float* xsrc = x + (size_t)(rows0 + arow) * DD + kc0 * 8;
  int aslot0, aslot1;
  if (split) {
    aslot0 = arow * 8 + (kc0 ^ (arow & 3));
    aslot1 = arow * 8 + ((kc0 + 1) ^ (arow & 3));
  } else {
    aslot0 = arow * 4 + (kc0 ^ ((arow >> 1) & 3));
    aslot1 = arow * 4 + ((kc0 + 1) ^ ((arow >> 1) & 3));
  }

  // ---- B staging constants (global_load_lds, dest linear = slot t+i*256)
  const int nbi = split ? 4 : 2;
  const _Float16* bsrc[4];
  #pragma unroll
  for (int i = 0; i < 4; ++i) {
    const int s = t + i * 256;
    int col, wsrc; const _Float16* base;
    if (split) {
      col = s >> 3;
      const int w = s & 7;
      wsrc = (w & 3) ^ (col & 3);
      base = (w >> 2) ? Wl : Wh;
    } else {
      col = (s & 511) >> 2;
      wsrc = (s & 3) ^ ((col >> 1) & 3);
      base = Wh;
    }
    bsrc[i] = base + (size_t)(cols0 + col) * DD + wsrc * 8;
  }

  for (int ks = 0; ks < 32; ++ks) {
    const int k0 = ks * BKS;
    if (ks) __syncthreads();                   // compute done before overwrite

    // B tiles: async global->LDS
    #pragma unroll
    for (int i = 0; i < 4; ++i)
      if (i < nbi) gload16(bsrc[i] + k0, &Bsm[(t + i * 256) * 8]);

    // A tile: fp32 load, split, ds_write (swizzled per-lane dest)
    {
      const float4 f0 = *(const float4*)(xsrc + k0);
      const float4 f1 = *(const float4*)(xsrc + k0 + 4);
      const float4 f2 = *(const float4*)(xsrc + k0 + 8);
      const float4 f3 = *(const float4*)(xsrc + k0 + 12);
      const float xv[16] = {f0.x, f0.y, f0.z, f0.w, f1.x, f1.y, f1.z, f1.w,
                            f2.x, f2.y, f2.z, f2.w, f3.x, f3.y, f3.z, f3.w};
      half8v h0, h1, lo0, lo1;
      #pragma unroll
      for (int j = 0; j < 8; ++j) {
        h0[j] = (_Float16)xv[j];
        lo0[j] = (_Float16)(xv[j] - (float)h0[j]);
        h1[j] = (_Float16)xv[8 + j];
        lo1[j] = (_Float16)(xv[8 + j] - (float)h1[j]);
      }
      *(half8v*)&Asm[aslot0 * 8] = h0;
      *(half8v*)&Asm[aslot1 * 8] = h1;
      if (split) {
        *(half8v*)&Asm[(aslot0 + 4) * 8] = lo0;
        *(half8v*)&Asm[(aslot1 + 4) * 8] = lo1;
      }
    }
    __syncthreads();                           // drains vmcnt+lgkm, then barrier

    #pragma unroll
    for (int kh2 = 0; kh2 < 2; ++kh2) {
      const int c = kh2 * 2 + lh;
      half8v ah[2], alv[2], bh[2], blv[2];
      #pragma unroll
      for (int wr = 0; wr < 2; ++wr) {
        const int row = warpR * 64 + wr * 32 + lr;
        if (split) {
          const int sl = row * 8 + (c ^ (row & 3));
          ah[wr] = *(const half8v*)&Asm[sl * 8];
          alv[wr] = *(const half8v*)&Asm[(sl + 4) * 8];
        } else {
          ah[wr] = *(const half8v*)&Asm[(row * 4 + (c ^ ((row >> 1) & 3))) * 8];
        }
      }
      #pragma unroll
      for (int wc = 0; wc < 2; ++wc) {
        const int col = warpC * 64 + wc * 32 + lr;
        if (split) {
          const int sl = col * 8 + (c ^ (col & 3));
          bh[wc] = *(const half8v*)&Bsm[sl * 8];
          blv[wc] = *(const half8v*)&Bsm[(sl + 4) * 8];
        } else {
          bh[wc] = *(const half8v*)&Bsm[(col * 4 + (c ^ ((col >> 1) & 3))) * 8];
        }
      }
      #pragma unroll
      for (int wr = 0; wr < 2; ++wr)
        #pragma unroll
        for (int wc = 0; wc < 2; ++wc) {
          acc[wr][wc] = __builtin_amdgcn_mfma_f32_32x32x16_f16(ah[wr], bh[wc], acc[wr][wc], 0, 0, 0);
          if (split) {
            acc[wr][wc] = __builtin_amdgcn_mfma_f32_32x32x16_f16(alv[wr], bh[wc], acc[wr][wc], 0, 0, 0);
            acc[wr][wc] = __builtin_amdgcn_mfma_f32_32x32x16_f16(ah[wr], blv[wc], acc[wr][wc], 0, 0, 0);
          }
        }
    }
  }

  // epilogue: head-split fp16 stores (hi + lo for Q/K)
  const int mb0 = rows0 + warpR * 64 + 4 * lh;
  #pragma unroll
  for (int wr = 0; wr < 2; ++wr)
    #pragma unroll
    for (int wc = 0; wc < 2; ++wc) {
      const int n = cols0 + warpC * 64 + wc * 32 + lr;
      const int h = n >> 6, d = n & 63;
      #pragma unroll
      for (int r = 0; r < 16; ++r) {
        const int m = mb0 + wr * 32 + (r & 3) + 8 * (r >> 2);
        const int b = m >> 11, srow = m & 2047;
        const size_t o = ((size_t)(b * HH + h) * SS + srow) * DP + d;
        const float a = acc[wr][wc][r];
        const _Float16 h16 = (_Float16)a;
        dhi[o] = h16;
        if (split) dlo[o] = (_Float16)(a - (float)h16);
      }
    }
}

// ---------------------------------------------------------------------------
// Mask scan -> compact key list padded to x32 with duplicates of the first
// masked key; writes real count (for validity masking) and padded count.
// ---------------------------------------------------------------------------
__global__ __launch_bounds__(256) void scan_kernel(
    const int* __restrict__ mask, int* __restrict__ klist,
    int* __restrict__ cntpad, int* __restrict__ cntreal)
{
  __shared__ int part[256];
  __shared__ int tot;
  const int b = blockIdx.x, t = threadIdx.x;
  int loc[8]; int c = 0;
  #pragma unroll
  for (int j = 0; j < 8; ++j) {
    loc[j] = (mask[(b << 11) + t * 8 + j] == 0);
    c += loc[j];
  }
  part[t] = c;
  __syncthreads();
  if (t == 0) {
    int run = 0;
    for (int i = 0; i < 256; ++i) { int v = part[i]; part[i] = run; run += v; }
    tot = run;
  }
  __syncthreads();
  int off = part[t];
  #pragma unroll
  for (int j = 0; j < 8; ++j)
    if (loc[j]) klist[(b << 11) + off++] = t * 8 + j;
  __syncthreads();
  if (t == 0) {
    int n = tot;
    int first;
    if (n == 0) { klist[b << 11] = 0; n = 1; first = 0; }
    else first = klist[b << 11];
    int np = (n + 31) & ~31;
    for (int i = n; i < np; ++i) klist[(b << 11) + i] = first;
    cntpad[b] = np;
    cntreal[b] = n;
  }
}

// ---------------------------------------------------------------------------
// MFMA masked-argmin filter, 3-pass fp16 hi/lo (score err ~1e-5).  Wave = one
// 32q tile; A=K rows via klist, B=Q cols; scores packed with 11-bit compact
// key index -> per-lane top-6 via fmed3.  Padded slots forced to +FLT_MAX.
// ---------------------------------------------------------------------------
__global__ __launch_bounds__(256) void filter_kernel(
    const _Float16* __restrict__ Qhi, const _Float16* __restrict__ Qlo,
    const _Float16* __restrict__ Khi, const _Float16* __restrict__ Klo,
    const int* __restrict__ klist, const int* __restrict__ cntpad,
    const int* __restrict__ cntreal,
    int* __restrict__ idx, int* __restrict__ ambr, int* __restrict__ ambc,
    int* __restrict__ cand, int* __restrict__ ccnt)
{
  const int bh = blockIdx.x >> 4;
  const int b = bh >> 4;
  const int wid = threadIdx.x >> 6;
  const int l = threadIdx.x & 63;
  const int q0 = ((blockIdx.x & 15) << 7) + (wid << 5);
  const int half = l >> 5;
  const int lq = l & 31;
  const int* __restrict__ kl_b = klist + (b << 11);

  half8v qh[4], ql[4];
  {
    const size_t qrow = ((size_t)bh * SS + q0 + lq) * DP + half * 8;
    #pragma unroll
    for (int ds = 0; ds < 4; ++ds) {
      qh[ds] = *(const half8v*)(Qhi + qrow + ds * 16);
      ql[ds] = *(const half8v*)(Qlo + qrow + ds * 16);
    }
  }

  const int nreal = cntreal[b];
  const int nt = cntpad[b] >> 5;
  float m1 = FLT_MAX, m2 = FLT_MAX, m3 = FLT_MAX,
        m4 = FLT_MAX, m5 = FLT_MAX, m6 = FLT_MAX;
  uint kidx[16];
  #pragma unroll
  for (int r = 0; r < 16; ++r)
    kidx[r] = (uint)((r & 3) + ((r >> 2) << 3) + (half << 2));

  const size_t kbase = (size_t)bh * SS;
  for (int t = 0; t < nt; ++t) {
    const int kval = kl_b[(t << 5) + lq];
    const size_t krow = (kbase + kval) * DP + half * 8;
    f32x16 acc;
    #pragma unroll
    for (int r = 0; r < 16; ++r) acc[r] = 0.f;
    #pragma unroll
    for (int ds = 0; ds < 4; ++ds) {
      const half8v kh = *(const half8v*)(Khi + krow + ds * 16);
      const half8v kl = *(const half8v*)(Klo + krow + ds * 16);
      acc = __builtin_amdgcn_mfma_f32_32x32x16_f16(kh, qh[ds], acc, 0, 0, 0);
      acc = __builtin_amdgcn_mfma_f32_32x32x16_f16(kh, ql[ds], acc, 0, 0, 0);
      acc = __builtin_amdgcn_mfma_f32_32x32x16_f16(kl, qh[ds], acc, 0, 0, 0);
    }
    const bool part = (t == nt - 1) && ((nreal & 31) != 0);
    #pragma unroll
    for (int r = 0; r < 16; ++r) {
      const uint pv = (__float_as_uint(acc[r]) & 0xFFFFF800u) | kidx[r];
      float v = __uint_as_float(pv);
      if (part && kidx[r] >= (uint)nreal) v = FLT_MAX;   // padded: never competes
      m6 = __builtin_amdgcn_fmed3f(v, m5, m6);
      m5 = __builtin_amdgcn_fmed3f(v, m4, m5);
      m4 = __builtin_amdgcn_fmed3f(v, m3, m4);
      m3 = __builtin_amdgcn_fmed3f(v, m2, m3);
      m2 = __builtin_amdgcn_fmed3f(v, m1, m2);
      m1 = fminf(v, m1);
      kidx[r] += 32;
    }
  }

  float om[6];
  om[0] = __shfl_xor(m1, 32, 64);
  om[1] = __shfl_xor(m2, 32, 64);
  om[2] = __shfl_xor(m3, 32, 64);
  om[3] = __shfl_xor(m4, 32, 64);
  om[4] = __shfl_xor(m5, 32, 64);
  om[5] = __shfl_xor(m6, 32, 64);
  #pragma unroll
  for (int j = 0; j < 6; ++j) {
    const float v = om[j];
    m6 = __builtin_amdgcn_fmed3f(v, m5, m6);
    m5 = __builtin_amdgcn_fmed3f(v, m4, m5);
    m4 = __builtin_amdgcn_fmed3f(v, m3, m4);
    m3 = __builtin_amdgcn_fmed3f(v, m2, m3);
    m2 = __builtin_amdgcn_fmed3f(v, m1, m2);
    m1 = fminf(v, m1);
  }

  if (half == 0) {
    const int row = bh * SS + q0 + lq;
    const uint u1 = __float_as_uint(m1);
    const int k1 = kl_b[u1 & 2047u];
    idx[row] = k1;
    const float v1 = __uint_as_float(u1 & 0xFFFFF800u);
    const uint us[5] = {__float_as_uint(m2), __float_as_uint(m3),
                        __float_as_uint(m4), __float_as_uint(m5),
                        __float_as_uint(m6)};
    const float v2 = __uint_as_float(us[0] & 0xFFFFF800u);
    if (v2 - v1 < MARGIN_F) {
      int c[6]; int n = 0;
      c[n++] = k1;
      #pragma unroll
      for (int j = 0; j < 5; ++j) {
        const float vj = __uint_as_float(us[j] & 0xFFFFF800u);
        if (vj - v1 < MARGIN_F) c[n++] = kl_b[us[j] & 2047u];
        else break;
      }
      const int pos = atomicAdd(ambc, 1);
      ambr[pos] = row;
      ccnt[row] = n;
      for (int j = 0; j < n; ++j) cand[row * 8 + j] = c[j];
    }
  }
}

// ---------------------------------------------------------------------------
// Two-tier refine.  Tier 1: f64 scores from reconstructed fp16 hi/lo Q,K.
// If the reconstructed top-2 gap < TIER2_TAU, tier 2 re-adjudicates ALL
// candidates with f64 ground truth from x,W columns.
// ---------------------------------------------------------------------------
__global__ __launch_bounds__(64) void refine_kernel(
    const _Float16* __restrict__ Qhi, const _Float16* __restrict__ Qlo,
    const _Float16* __restrict__ Khi, const _Float16* __restrict__ Klo,
    const float* __restrict__ x, const float* __restrict__ Wq,
    const float* __restrict__ Wk,
    const int* __restrict__ ambr, const int* __restrict__ ambc,
    const int* __restrict__ cand, const int* __restrict__ ccnt,
    int* __restrict__ idx)
{
  const int n = *ambc;
  const int lane = threadIdx.x;
  for (int it = blockIdx.x; it < n; it += gridDim.x) {
    const int row = ambr[it];
    const int bh = row >> 11;
    const int cnum = ccnt[row];

    // ---- tier 1: reconstructed-score ranking ----
    const size_t qb = (size_t)row * DP;
    const double q = (double)(float)Qhi[qb + lane] + (double)(float)Qlo[qb + lane];
    double best = 1e300, best2 = 1e300; int bi = 0x7fffffff;
    for (int c = 0; c < cnum; ++c) {
      const int k = cand[row * 8 + c] & 2047;
      const size_t kb = ((size_t)bh * SS + k) * DP;
      const double kv = (double)(float)Khi[kb + lane] + (double)(float)Klo[kb + lane];
      double p = q * kv;
      #pragma unroll
      for (int o = 32; o > 0; o >>= 1) p += __shfl_xor(p, o, 64);
      if (p < best) { best2 = best; best = p; bi = k; }
      else if (p < best2) best2 = p;
    }

    // ---- tier 2: ground truth from x,W when recon gap is too small ----
    if (best2 - best < TIER2_TAU) {
      const int qq = row & 2047;
      const int b = bh >> 4, h = bh & 15;
      const int wc = (h << 6) + lane;
      const float* xq = x + ((size_t)(b << 11) + qq) * DD;
      double a0 = 0.0, a1 = 0.0, a2 = 0.0, a3 = 0.0;
      for (int j = 0; j < DD; j += 4) {
        a0 = fma((double)xq[j + 0], (double)Wq[(size_t)(j + 0) * DD + wc], a0);
        a1 = fma((double)xq[j + 1], (double)Wq[(size_t)(j + 1) * DD + wc], a1);
        a2 = fma((double)xq[j + 2], (double)Wq[(size_t)(j + 2) * DD + wc], a2);
        a3 = fma((double)xq[j + 3], (double)Wq[(size_t)(j + 3) * DD + wc], a3);
      }
      const double qd = (a0 + a1) + (a2 + a3);
      best = 1e300; bi = 0x7fffffff;
      for (int c = 0; c < cnum; ++c) {
        const int k = cand[row * 8 + c] & 2047;
        const float* xk = x + ((size_t)(b << 11) + k) * DD;
        double b0 = 0.0, b1 = 0.0, b2 = 0.0, b3 = 0.0;
        for (int j = 0; j < DD; j += 4) {
          b0 = fma((double)xk[j + 0], (double)Wk[(size_t)(j + 0) * DD + wc], b0);
          b1 = fma((double)xk[j + 1], (double)Wk[(size_t)(j + 1) * DD + wc], b1);
          b2 = fma((double)xk[j + 2], (double)Wk[(size_t)(j + 2) * DD + wc], b2);
          b3 = fma((double)xk[j + 3], (double)Wk[(size_t)(j + 3) * DD + wc], b3);
        }
        const double kd = (b0 + b1) + (b2 + b3);
        double p = qd * kd;
        #pragma unroll
        for (int o = 32; o > 0; o >>= 1) p += __shfl_xor(p, o, 64);
        if (p < best || (p == best && k < bi)) { best = p; bi = k; }
      }
    }
    if (lane == 0) idx[row] = bi;
  }
}

// ---------------------------------------------------------------------------
// fp16 MFMA out-projection: A = gathered V rows (one-hot attention), B = Woh
// [n][k]; epilogue bias + inference BN, fp32 store.
// ---------------------------------------------------------------------------
__global__ __launch_bounds__(256) void out_mfma(
    const _Float16* __restrict__ Vh, const int* __restrict__ idx,
    const _Float16* __restrict__ Woh, const float* __restrict__ bo,
    const float* __restrict__ gamma, const float* __restrict__ beta,
    const float* __restrict__ mmean, const float* __restrict__ mvar,
    float* __restrict__ out)
{
  const int rows0 = blockIdx.x * 128, cols0 = blockIdx.y * 128;
  const int w = threadIdx.x >> 6, l = threadIdx.x & 63;
  const int lr = l & 31, hi8 = (l >> 5) * 8;
  const int m = rows0 + w * 32 + lr;
  const int b = m >> 11, srow = m & 2047;

  int vidx[16];
  #pragma unroll
  for (int h = 0; h < 16; ++h)
    vidx[h] = idx[(size_t)(b * HH + h) * SS + srow];

  size_t brow[4];
  #pragma unroll
  for (int cf = 0; cf < 4; ++cf)
    brow[cf] = (size_t)(cols0 + cf * 32 + lr) * DD + hi8;

  f32x16 acc[4];
  #pragma unroll
  for (int cf = 0; cf < 4; ++cf)
    #pragma unroll
    for (int r = 0; r < 16; ++r) acc[cf][r] = 0.f;

  #pragma unroll 4
  for (int s = 0; s < 64; ++s) {
    const int h = s >> 2;
    const int kk = (s & 3) * 16 + hi8;
    half8v a = *(const half8v*)(Vh + ((size_t)(b * HH + h) * SS + vidx[h]) * DP + kk);
    #pragma unroll
    for (int cf = 0; cf < 4; ++cf) {
      half8v bf = *(const half8v*)(Woh + brow[cf] + s * 16);
      acc[cf] = __builtin_amdgcn_mfma_f32_32x32x16_f16(a, bf, acc[cf], 0, 0, 0);
    }
  }

  const int m_base = rows0 + w * 32 + 4 * (l >> 5);
  #pragma unroll
  for (int cf = 0; cf < 4; ++cf) {
    const int n = cols0 + cf * 32 + lr;
    const float sc = gamma[n] * rsqrtf(mvar[n] + 1e-3f);
    const float ofs = (bo[n] - mmean[n]) * sc + beta[n];
    #pragma unroll
    for (int r = 0; r < 16; ++r) {
      const int mr = m_base + (r & 3) + 8 * (r >> 2);
      out[(size_t)mr * DD + n] = acc[cf][r] * sc + ofs;
    }
  }
}

// ---------------------------------------------------------------------------
extern "C" void kernel_launch(void* const* d_in, const int* in_sizes, int n_in,
                              void* d_out, int out_size, void* d_ws, size_t ws_size,
                              hipStream_t stream)
{
  const float* x  = (const float*)d_in[0];
  const int* mask = (const int*)d_in[1];
  const float* Wq = (const float*)d_in[2];
  const float* Wk = (const float*)d_in[3];
  const float* Wv = (const float*)d_in[4];
  const float* Wo = (const float*)d_in[5];
  const float* bo = (const float*)d_in[6];
  const float* ga = (const float*)d_in[7];
  const float* be = (const float*)d_in[8];
  const float* mm = (const float*)d_in[9];
  const float* mv = (const float*)d_in[10];
  float* out = (float*)d_out;

  char* ws = (char*)d_ws;
  _Float16* Qhi = (_Float16*)(ws + 0);          // 16 MB
  _Float16* Qlo = (_Float16*)(ws + 16777216);   // 16 MB
  _Float16* Khi = (_Float16*)(ws + 33554432);   // 16 MB
  _Float16* Klo = (_Float16*)(ws + 50331648);   // 16 MB
  _Float16* Vh  = (_Float16*)(ws + 67108864);   // 16 MB
  _Float16* Wqh = (_Float16*)(ws + 83886080);   // 2 MB
  _Float16* Wql = (_Float16*)(ws + 85983232);   // 2 MB
  _Float16* Wkh = (_Float16*)(ws + 88080384);   // 2 MB
  _Float16* Wkl = (_Float16*)(ws + 90177536);   // 2 MB
  _Float16* Wvh = (_Float16*)(ws + 92274688);   // 2 MB
  _Float16* Woh = (_Float16*)(ws + 94371840);   // 2 MB
  int* klist    = (int*)(ws + 96468992);        // 32 KB
  int* cntp     = (int*)(ws + 96501760);        // 128 B
  int* cntn     = (int*)(ws + 96501888);        // 128 B
  int* idx      = (int*)(ws + 96502016);        // 512 KB
  int* ambr     = (int*)(ws + 97026304);        // 512 KB
  int* ambc     = (int*)(ws + 97550592);        // 128 B
  int* ccnt     = (int*)(ws + 97550720);        // 512 KB
  int* cnd      = (int*)(ws + 98075008);        // 4 MB (end ~97.5 MB)

  hipMemsetAsync(ambc, 0, 4, stream);
  wtrans_kernel<<<dim3(16, 16, 4), 256, 0, stream>>>(Wq, Wk, Wv, Wo,
                                                     Wqh, Wql, Wkh, Wkl, Wvh, Woh);
  scan_kernel<<<BB, 256, 0, stream>>>(mask, klist, cntp, cntn);
  proj_mfma<<<dim3(64, 8, 3), 256, 0, stream>>>(x, Wqh, Wql, Wkh, Wkl, Wvh,
                                                Qhi, Qlo, Khi, Klo, Vh);
  filter_kernel<<<1024, 256, 0, stream>>>(Qhi, Qlo, Khi, Klo, klist, cntp, cntn,
                                          idx, ambr, ambc, cnd, ccnt);
  refine_kernel<<<2048, 64, 0, stream>>>(Qhi, Qlo, Khi, Klo, x, Wq, Wk,
                                         ambr, ambc, cnd, ccnt, idx);
  out_mfma<<<dim3(64, 8), 256, 0, stream>>>(Vh, idx, Woh, bo, ga, be, mm, mv, out);
}

// Round 9
// 469.453 us; speedup vs baseline: 5.2381x; 1.1693x over previous
//
#include <hip/hip_runtime.h>
#include <hip/hip_bf16.h>
#include <float.h>

#define BB 4
#define SS 2048
#define DD 1024
#define HH 16
#define DP 64
#define BKS 32
#define MARGIN_F 0.02f   /* >= 2*packing_ulp(3.9e-3) + 3-pass filter err, 2.5x headroom */
#define TIER2_TAU 1e-4   /* recon-gap below this -> ground-truth re-adjudication */

typedef __attribute__((ext_vector_type(8))) _Float16 half8v;
typedef __attribute__((ext_vector_type(16))) float f32x16;

typedef __attribute__((address_space(3))) void lds_void;
typedef const __attribute__((address_space(1))) void gbl_void;
static __device__ __forceinline__ void gload16(const void* g, void* l) {
  __builtin_amdgcn_global_load_lds((gbl_void*)g, (lds_void*)l, 16, 0, 0);
}

// ---------------------------------------------------------------------------
// Prep: transpose W[k][n] f32 -> Wt[n][k] fp16 hi (+ fp16 lo residual for
// Wq,Wk).  z: 0=Wq(hi+lo) 1=Wk(hi+lo) 2=Wv(hi) 3=Wo(hi).
// ---------------------------------------------------------------------------
__global__ __launch_bounds__(256) void wtrans_kernel(
    const float* __restrict__ Wq, const float* __restrict__ Wk,
    const float* __restrict__ Wv, const float* __restrict__ Wo,
    _Float16* __restrict__ Wqh, _Float16* __restrict__ Wql,
    _Float16* __restrict__ Wkh, _Float16* __restrict__ Wkl,
    _Float16* __restrict__ Wvh, _Float16* __restrict__ Woh)
{
  const int z = blockIdx.z;
  const float* __restrict__ src = (z == 0) ? Wq : (z == 1 ? Wk : (z == 2 ? Wv : Wo));
  _Float16* __restrict__ dh = (z == 0) ? Wqh : (z == 1 ? Wkh : (z == 2 ? Wvh : Woh));
  _Float16* __restrict__ dl = (z == 0) ? Wql : Wkl;
  __shared__ float tile[64][65];
  const int k0 = blockIdx.x * 64, n0 = blockIdx.y * 64;
  const int c = threadIdx.x & 63, rb = threadIdx.x >> 6;
  #pragma unroll
  for (int i = 0; i < 16; ++i)
    tile[rb + 4 * i][c] = src[(size_t)(k0 + rb + 4 * i) * DD + n0 + c];
  __syncthreads();
  #pragma unroll
  for (int i = 0; i < 16; ++i) {
    const int n = n0 + rb + 4 * i;
    const float v = tile[c][rb + 4 * i];
    const _Float16 h = (_Float16)v;
    dh[(size_t)n * DD + k0 + c] = h;
    if (z < 2) dl[(size_t)n * DD + k0 + c] = (_Float16)(v - (float)h);
  }
}

// ---------------------------------------------------------------------------
// LDS-staged fp16 MFMA projection GEMM (m97-class structure).  Unchanged
// from round 8 (195 us, MfmaUtil 26%).
// ---------------------------------------------------------------------------
__global__ __launch_bounds__(256) void proj_mfma(
    const float* __restrict__ x,
    const _Float16* __restrict__ Wqh, const _Float16* __restrict__ Wql,
    const _Float16* __restrict__ Wkh, const _Float16* __restrict__ Wkl,
    const _Float16* __restrict__ Wvh,
    _Float16* __restrict__ Qhi, _Float16* __restrict__ Qlo,
    _Float16* __restrict__ Khi, _Float16* __restrict__ Klo,
    _Float16* __restrict__ Vh)
{
  const int z = blockIdx.z;
  const bool split = (z < 2);
  const _Float16* __restrict__ Wh = (z == 0) ? Wqh : (z == 1 ? Wkh : Wvh);
  const _Float16* __restrict__ Wl = (z == 0) ? Wql : Wkl;
  _Float16* __restrict__ dhi = (z == 0) ? Qhi : (z == 1 ? Khi : Vh);
  _Float16* __restrict__ dlo = (z == 0) ? Qlo : Klo;

  __shared__ _Float16 Asm[8192];
  __shared__ _Float16 Bsm[8192];

  const int rows0 = blockIdx.x * 128, cols0 = blockIdx.y * 128;
  const int t = threadIdx.x;
  const int wid = t >> 6, l = t & 63;
  const int warpR = wid >> 1, warpC = wid & 1;
  const int lr = l & 31, lh = l >> 5;

  f32x16 acc[2][2];
  #pragma unroll
  for (int i = 0; i < 2; ++i)
    #pragma unroll
    for (int j = 0; j < 2; ++j)
      #pragma unroll
      for (int r = 0; r < 16; ++r) acc[i][j][r] = 0.f;

  const int arow = t >> 1;
  const int kc0 = (t & 1) * 2;
  const float* xsrc = x + (size_t)(rows0 + arow) * DD + kc0 * 8;
  int aslot0, aslot1;
  if (split) {
    aslot0 = arow * 8 + (kc0 ^ (arow & 3));
    aslot1 = arow * 8 + ((kc0 + 1) ^ (arow & 3));
  } else {
    aslot0 = arow * 4 + (kc0 ^ ((arow >> 1) & 3));
    aslot1 = arow * 4 + ((kc0 + 1) ^ ((arow >> 1) & 3));
  }

  const int nbi = split ? 4 : 2;
  const _Float16* bsrc[4];
  #pragma unroll
  for (int i = 0; i < 4; ++i) {
    const int s = t + i * 256;
    int col, wsrc; const _Float16* base;
    if (split) {
      col = s >> 3;
      const int w = s & 7;
      wsrc = (w & 3) ^ (col & 3);
      base = (w >> 2) ? Wl : Wh;
    } else {
      col = (s & 511) >> 2;
      wsrc = (s & 3) ^ ((col >> 1) & 3);
      base = Wh;
    }
    bsrc[i] = base + (size_t)(cols0 + col) * DD + wsrc * 8;
  }

  for (int ks = 0; ks < 32; ++ks) {
    const int k0 = ks * BKS;
    if (ks) __syncthreads();

    #pragma unroll
    for (int i = 0; i < 4; ++i)
      if (i < nbi) gload16(bsrc[i] + k0, &Bsm[(t + i * 256) * 8]);

    {
      const float4 f0 = *(const float4*)(xsrc + k0);
      const float4 f1 = *(const float4*)(xsrc + k0 + 4);
      const float4 f2 = *(const float4*)(xsrc + k0 + 8);
      const float4 f3 = *(const float4*)(xsrc + k0 + 12);
      const float xv[16] = {f0.x, f0.y, f0.z, f0.w, f1.x, f1.y, f1.z, f1.w,
                            f2.x, f2.y, f2.z, f2.w, f3.x, f3.y, f3.z, f3.w};
      half8v h0, h1, lo0, lo1;
      #pragma unroll
      for (int j = 0; j < 8; ++j) {
        h0[j] = (_Float16)xv[j];
        lo0[j] = (_Float16)(xv[j] - (float)h0[j]);
        h1[j] = (_Float16)xv[8 + j];
        lo1[j] = (_Float16)(xv[8 + j] - (float)h1[j]);
      }
      *(half8v*)&Asm[aslot0 * 8] = h0;
      *(half8v*)&Asm[aslot1 * 8] = h1;
      if (split) {
        *(half8v*)&Asm[(aslot0 + 4) * 8] = lo0;
        *(half8v*)&Asm[(aslot1 + 4) * 8] = lo1;
      }
    }
    __syncthreads();

    #pragma unroll
    for (int kh2 = 0; kh2 < 2; ++kh2) {
      const int c = kh2 * 2 + lh;
      half8v ah[2], alv[2], bh[2], blv[2];
      #pragma unroll
      for (int wr = 0; wr < 2; ++wr) {
        const int row = warpR * 64 + wr * 32 + lr;
        if (split) {
          const int sl = row * 8 + (c ^ (row & 3));
          ah[wr] = *(const half8v*)&Asm[sl * 8];
          alv[wr] = *(const half8v*)&Asm[(sl + 4) * 8];
        } else {
          ah[wr] = *(const half8v*)&Asm[(row * 4 + (c ^ ((row >> 1) & 3))) * 8];
        }
      }
      #pragma unroll
      for (int wc = 0; wc < 2; ++wc) {
        const int col = warpC * 64 + wc * 32 + lr;
        if (split) {
          const int sl = col * 8 + (c ^ (col & 3));
          bh[wc] = *(const half8v*)&Bsm[sl * 8];
          blv[wc] = *(const half8v*)&Bsm[(sl + 4) * 8];
        } else {
          bh[wc] = *(const half8v*)&Bsm[(col * 4 + (c ^ ((col >> 1) & 3))) * 8];
        }
      }
      #pragma unroll
      for (int wr = 0; wr < 2; ++wr)
        #pragma unroll
        for (int wc = 0; wc < 2; ++wc) {
          acc[wr][wc] = __builtin_amdgcn_mfma_f32_32x32x16_f16(ah[wr], bh[wc], acc[wr][wc], 0, 0, 0);
          if (split) {
            acc[wr][wc] = __builtin_amdgcn_mfma_f32_32x32x16_f16(alv[wr], bh[wc], acc[wr][wc], 0, 0, 0);
            acc[wr][wc] = __builtin_amdgcn_mfma_f32_32x32x16_f16(ah[wr], blv[wc], acc[wr][wc], 0, 0, 0);
          }
        }
    }
  }

  const int mb0 = rows0 + warpR * 64 + 4 * lh;
  #pragma unroll
  for (int wr = 0; wr < 2; ++wr)
    #pragma unroll
    for (int wc = 0; wc < 2; ++wc) {
      const int n = cols0 + warpC * 64 + wc * 32 + lr;
      const int h = n >> 6, d = n & 63;
      #pragma unroll
      for (int r = 0; r < 16; ++r) {
        const int m = mb0 + wr * 32 + (r & 3) + 8 * (r >> 2);
        const int b = m >> 11, srow = m & 2047;
        const size_t o = ((size_t)(b * HH + h) * SS + srow) * DP + d;
        const float a = acc[wr][wc][r];
        const _Float16 h16 = (_Float16)a;
        dhi[o] = h16;
        if (split) dlo[o] = (_Float16)(a - (float)h16);
      }
    }
}

// ---------------------------------------------------------------------------
// Mask scan -> compact key list padded to x32 with duplicates of the first
// masked key; writes real count (for validity masking) and padded count.
// ---------------------------------------------------------------------------
__global__ __launch_bounds__(256) void scan_kernel(
    const int* __restrict__ mask, int* __restrict__ klist,
    int* __restrict__ cntpad, int* __restrict__ cntreal)
{
  __shared__ int part[256];
  __shared__ int tot;
  const int b = blockIdx.x, t = threadIdx.x;
  int loc[8]; int c = 0;
  #pragma unroll
  for (int j = 0; j < 8; ++j) {
    loc[j] = (mask[(b << 11) + t * 8 + j] == 0);
    c += loc[j];
  }
  part[t] = c;
  __syncthreads();
  if (t == 0) {
    int run = 0;
    for (int i = 0; i < 256; ++i) { int v = part[i]; part[i] = run; run += v; }
    tot = run;
  }
  __syncthreads();
  int off = part[t];
  #pragma unroll
  for (int j = 0; j < 8; ++j)
    if (loc[j]) klist[(b << 11) + off++] = t * 8 + j;
  __syncthreads();
  if (t == 0) {
    int n = tot;
    int first;
    if (n == 0) { klist[b << 11] = 0; n = 1; first = 0; }
    else first = klist[b << 11];
    int np = (n + 31) & ~31;
    for (int i = n; i < np; ++i) klist[(b << 11) + i] = first;
    cntpad[b] = np;
    cntreal[b] = n;
  }
}

// ---------------------------------------------------------------------------
// MFMA masked-argmin filter, 3-pass fp16 hi/lo.  Unchanged from round 8.
// ---------------------------------------------------------------------------
__global__ __launch_bounds__(256) void filter_kernel(
    const _Float16* __restrict__ Qhi, const _Float16* __restrict__ Qlo,
    const _Float16* __restrict__ Khi, const _Float16* __restrict__ Klo,
    const int* __restrict__ klist, const int* __restrict__ cntpad,
    const int* __restrict__ cntreal,
    int* __restrict__ idx, int* __restrict__ ambr, int* __restrict__ ambc,
    int* __restrict__ cand, int* __restrict__ ccnt)
{
  const int bh = blockIdx.x >> 4;
  const int b = bh >> 4;
  const int wid = threadIdx.x >> 6;
  const int l = threadIdx.x & 63;
  const int q0 = ((blockIdx.x & 15) << 7) + (wid << 5);
  const int half = l >> 5;
  const int lq = l & 31;
  const int* __restrict__ kl_b = klist + (b << 11);

  half8v qh[4], ql[4];
  {
    const size_t qrow = ((size_t)bh * SS + q0 + lq) * DP + half * 8;
    #pragma unroll
    for (int ds = 0; ds < 4; ++ds) {
      qh[ds] = *(const half8v*)(Qhi + qrow + ds * 16);
      ql[ds] = *(const half8v*)(Qlo + qrow + ds * 16);
    }
  }

  const int nreal = cntreal[b];
  const int nt = cntpad[b] >> 5;
  float m1 = FLT_MAX, m2 = FLT_MAX, m3 = FLT_MAX,
        m4 = FLT_MAX, m5 = FLT_MAX, m6 = FLT_MAX;
  uint kidx[16];
  #pragma unroll
  for (int r = 0; r < 16; ++r)
    kidx[r] = (uint)((r & 3) + ((r >> 2) << 3) + (half << 2));

  const size_t kbase = (size_t)bh * SS;
  for (int t = 0; t < nt; ++t) {
    const int kval = kl_b[(t << 5) + lq];
    const size_t krow = (kbase + kval) * DP + half * 8;
    f32x16 acc;
    #pragma unroll
    for (int r = 0; r < 16; ++r) acc[r] = 0.f;
    #pragma unroll
    for (int ds = 0; ds < 4; ++ds) {
      const half8v kh = *(const half8v*)(Khi + krow + ds * 16);
      const half8v kl = *(const half8v*)(Klo + krow + ds * 16);
      acc = __builtin_amdgcn_mfma_f32_32x32x16_f16(kh, qh[ds], acc, 0, 0, 0);
      acc = __builtin_amdgcn_mfma_f32_32x32x16_f16(kh, ql[ds], acc, 0, 0, 0);
      acc = __builtin_amdgcn_mfma_f32_32x32x16_f16(kl, qh[ds], acc, 0, 0, 0);
    }
    const bool part = (t == nt - 1) && ((nreal & 31) != 0);
    #pragma unroll
    for (int r = 0; r < 16; ++r) {
      const uint pv = (__float_as_uint(acc[r]) & 0xFFFFF800u) | kidx[r];
      float v = __uint_as_float(pv);
      if (part && kidx[r] >= (uint)nreal) v = FLT_MAX;
      m6 = __builtin_amdgcn_fmed3f(v, m5, m6);
      m5 = __builtin_amdgcn_fmed3f(v, m4, m5);
      m4 = __builtin_amdgcn_fmed3f(v, m3, m4);
      m3 = __builtin_amdgcn_fmed3f(v, m2, m3);
      m2 = __builtin_amdgcn_fmed3f(v, m1, m2);
      m1 = fminf(v, m1);
      kidx[r] += 32;
    }
  }

  float om[6];
  om[0] = __shfl_xor(m1, 32, 64);
  om[1] = __shfl_xor(m2, 32, 64);
  om[2] = __shfl_xor(m3, 32, 64);
  om[3] = __shfl_xor(m4, 32, 64);
  om[4] = __shfl_xor(m5, 32, 64);
  om[5] = __shfl_xor(m6, 32, 64);
  #pragma unroll
  for (int j = 0; j < 6; ++j) {
    const float v = om[j];
    m6 = __builtin_amdgcn_fmed3f(v, m5, m6);
    m5 = __builtin_amdgcn_fmed3f(v, m4, m5);
    m4 = __builtin_amdgcn_fmed3f(v, m3, m4);
    m3 = __builtin_amdgcn_fmed3f(v, m2, m3);
    m2 = __builtin_amdgcn_fmed3f(v, m1, m2);
    m1 = fminf(v, m1);
  }

  if (half == 0) {
    const int row = bh * SS + q0 + lq;
    const uint u1 = __float_as_uint(m1);
    const int k1 = kl_b[u1 & 2047u];
    idx[row] = k1;
    const float v1 = __uint_as_float(u1 & 0xFFFFF800u);
    const uint us[5] = {__float_as_uint(m2), __float_as_uint(m3),
                        __float_as_uint(m4), __float_as_uint(m5),
                        __float_as_uint(m6)};
    const float v2 = __uint_as_float(us[0] & 0xFFFFF800u);
    if (v2 - v1 < MARGIN_F) {
      int c[6]; int n = 0;
      c[n++] = k1;
      #pragma unroll
      for (int j = 0; j < 5; ++j) {
        const float vj = __uint_as_float(us[j] & 0xFFFFF800u);
        if (vj - v1 < MARGIN_F) c[n++] = kl_b[us[j] & 2047u];
        else break;
      }
      const int pos = atomicAdd(ambc, 1);
      ambr[pos] = row;
      ccnt[row] = n;
      for (int j = 0; j < n; ++j) cand[row * 8 + j] = c[j];
    }
  }
}

// ---------------------------------------------------------------------------
// Two-tier refine, latency-optimized.  One row per block (256 thr, 4 waves).
// Tier 1 (all waves redundantly, block-uniform result): f64 recon scores.
// Tier 2 (~15 rows): j-dim split across the 4 waves, Q + all candidates
// FUSED into one j-loop with named f64 accumulators; LDS partial reduce.
// ---------------------------------------------------------------------------
__global__ __launch_bounds__(256) void refine_kernel(
    const _Float16* __restrict__ Qhi, const _Float16* __restrict__ Qlo,
    const _Float16* __restrict__ Khi, const _Float16* __restrict__ Klo,
    const float* __restrict__ x, const float* __restrict__ Wq,
    const float* __restrict__ Wk,
    const int* __restrict__ ambr, const int* __restrict__ ambc,
    const int* __restrict__ cand, const int* __restrict__ ccnt,
    int* __restrict__ idx)
{
  __shared__ double red[4][7][64];   // [wave][qd|kd0..kd5][wc]  14 KB
  const int n = *ambc;
  const int t = threadIdx.x;
  const int w = t >> 6, lane = t & 63;

  for (int it = blockIdx.x; it < n; it += gridDim.x) {
    const int row = ambr[it];
    const int bh = row >> 11;
    const int cnum = ccnt[row];

    // ---- tier 1 (identical on every wave -> block-uniform branch) ----
    const size_t qb = (size_t)row * DP;
    const double q = (double)(float)Qhi[qb + lane] + (double)(float)Qlo[qb + lane];
    double best = 1e300, best2 = 1e300; int bi = 0x7fffffff;
    for (int c = 0; c < cnum; ++c) {
      const int k = cand[row * 8 + c] & 2047;
      const size_t kb = ((size_t)bh * SS + k) * DP;
      const double kv = (double)(float)Khi[kb + lane] + (double)(float)Klo[kb + lane];
      double p = q * kv;
      #pragma unroll
      for (int o = 32; o > 0; o >>= 1) p += __shfl_xor(p, o, 64);
      if (p < best) { best2 = best; best = p; bi = k; }
      else if (p < best2) best2 = p;
    }

    if (best2 - best < TIER2_TAU) {
      // ---- tier 2: ground truth from x,W; j split across waves, fused ----
      const int qq = row & 2047;
      const int b = bh >> 4, h = bh & 15;
      const int wc = (h << 6) + lane;
      const float* xq = x + ((size_t)(b << 11) + qq) * DD;
      int kk[6];
      #pragma unroll
      for (int c = 0; c < 6; ++c)
        kk[c] = cand[row * 8 + (c < cnum ? c : 0)] & 2047;
      const float* xk0 = x + ((size_t)(b << 11) + kk[0]) * DD;
      const float* xk1 = x + ((size_t)(b << 11) + kk[1]) * DD;
      const float* xk2 = x + ((size_t)(b << 11) + kk[2]) * DD;
      const float* xk3 = x + ((size_t)(b << 11) + kk[3]) * DD;
      const float* xk4 = x + ((size_t)(b << 11) + kk[4]) * DD;
      const float* xk5 = x + ((size_t)(b << 11) + kk[5]) * DD;

      double qd = 0.0, kd0 = 0.0, kd1 = 0.0, kd2 = 0.0,
             kd3 = 0.0, kd4 = 0.0, kd5 = 0.0;
      const int j0 = w * 256;
      #pragma unroll 4
      for (int j = j0; j < j0 + 256; ++j) {
        const double wq = (double)Wq[(size_t)j * DD + wc];
        const double wk = (double)Wk[(size_t)j * DD + wc];
        qd  = fma((double)xq[j],  wq, qd);
        kd0 = fma((double)xk0[j], wk, kd0);
        kd1 = fma((double)xk1[j], wk, kd1);
        kd2 = fma((double)xk2[j], wk, kd2);
        kd3 = fma((double)xk3[j], wk, kd3);
        kd4 = fma((double)xk4[j], wk, kd4);
        kd5 = fma((double)xk5[j], wk, kd5);
      }
      red[w][0][lane] = qd;
      red[w][1][lane] = kd0; red[w][2][lane] = kd1; red[w][3][lane] = kd2;
      red[w][4][lane] = kd3; red[w][5][lane] = kd4; red[w][6][lane] = kd5;
      __syncthreads();

      if (w == 0) {
        const double qs = red[0][0][lane] + red[1][0][lane] +
                          red[2][0][lane] + red[3][0][lane];
        best = 1e300; bi = 0x7fffffff;
        for (int c = 0; c < cnum; ++c) {
          const double ks = red[0][1 + c][lane] + red[1][1 + c][lane] +
                            red[2][1 + c][lane] + red[3][1 + c][lane];
          double p = qs * ks;
          #pragma unroll
          for (int o = 32; o > 0; o >>= 1) p += __shfl_xor(p, o, 64);
          const int k = kk[c];
          if (p < best || (p == best && k < bi)) { best = p; bi = k; }
        }
        if (lane == 0) idx[row] = bi;
      }
      __syncthreads();   // protect LDS before next grid-stride row
    } else {
      if (t == 0) idx[row] = bi;
    }
  }
}

// ---------------------------------------------------------------------------
// fp16 MFMA out-projection: A = gathered V rows (one-hot attention), B = Woh
// [n][k]; epilogue bias + inference BN, fp32 store.  Unchanged.
// ---------------------------------------------------------------------------
__global__ __launch_bounds__(256) void out_mfma(
    const _Float16* __restrict__ Vh, const int* __restrict__ idx,
    const _Float16* __restrict__ Woh, const float* __restrict__ bo,
    const float* __restrict__ gamma, const float* __restrict__ beta,
    const float* __restrict__ mmean, const float* __restrict__ mvar,
    float* __restrict__ out)
{
  const int rows0 = blockIdx.x * 128, cols0 = blockIdx.y * 128;
  const int w = threadIdx.x >> 6, l = threadIdx.x & 63;
  const int lr = l & 31, hi8 = (l >> 5) * 8;
  const int m = rows0 + w * 32 + lr;
  const int b = m >> 11, srow = m & 2047;

  int vidx[16];
  #pragma unroll
  for (int h = 0; h < 16; ++h)
    vidx[h] = idx[(size_t)(b * HH + h) * SS + srow];

  size_t brow[4];
  #pragma unroll
  for (int cf = 0; cf < 4; ++cf)
    brow[cf] = (size_t)(cols0 + cf * 32 + lr) * DD + hi8;

  f32x16 acc[4];
  #pragma unroll
  for (int cf = 0; cf < 4; ++cf)
    #pragma unroll
    for (int r = 0; r < 16; ++r) acc[cf][r] = 0.f;

  #pragma unroll 4
  for (int s = 0; s < 64; ++s) {
    const int h = s >> 2;
    const int kk = (s & 3) * 16 + hi8;
    half8v a = *(const half8v*)(Vh + ((size_t)(b * HH + h) * SS + vidx[h]) * DP + kk);
    #pragma unroll
    for (int cf = 0; cf < 4; ++cf) {
      half8v bf = *(const half8v*)(Woh + brow[cf] + s * 16);
      acc[cf] = __builtin_amdgcn_mfma_f32_32x32x16_f16(a, bf, acc[cf], 0, 0, 0);
    }
  }

  const int m_base = rows0 + w * 32 + 4 * (l >> 5);
  #pragma unroll
  for (int cf = 0; cf < 4; ++cf) {
    const int n = cols0 + cf * 32 + lr;
    const float sc = gamma[n] * rsqrtf(mvar[n] + 1e-3f);
    const float ofs = (bo[n] - mmean[n]) * sc + beta[n];
    #pragma unroll
    for (int r = 0; r < 16; ++r) {
      const int mr = m_base + (r & 3) + 8 * (r >> 2);
      out[(size_t)mr * DD + n] = acc[cf][r] * sc + ofs;
    }
  }
}

// ---------------------------------------------------------------------------
extern "C" void kernel_launch(void* const* d_in, const int* in_sizes, int n_in,
                              void* d_out, int out_size, void* d_ws, size_t ws_size,
                              hipStream_t stream)
{
  const float* x  = (const float*)d_in[0];
  const int* mask = (const int*)d_in[1];
  const float* Wq = (const float*)d_in[2];
  const float* Wk = (const float*)d_in[3];
  const float* Wv = (const float*)d_in[4];
  const float* Wo = (const float*)d_in[5];
  const float* bo = (const float*)d_in[6];
  const float* ga = (const float*)d_in[7];
  const float* be = (const float*)d_in[8];
  const float* mm = (const float*)d_in[9];
  const float* mv = (const float*)d_in[10];
  float* out = (float*)d_out;

  char* ws = (char*)d_ws;
  _Float16* Qhi = (_Float16*)(ws + 0);          // 16 MB
  _Float16* Qlo = (_Float16*)(ws + 16777216);   // 16 MB
  _Float16* Khi = (_Float16*)(ws + 33554432);   // 16 MB
  _Float16* Klo = (_Float16*)(ws + 50331648);   // 16 MB
  _Float16* Vh  = (_Float16*)(ws + 67108864);   // 16 MB
  _Float16* Wqh = (_Float16*)(ws + 83886080);   // 2 MB
  _Float16* Wql = (_Float16*)(ws + 85983232);   // 2 MB
  _Float16* Wkh = (_Float16*)(ws + 88080384);   // 2 MB
  _Float16* Wkl = (_Float16*)(ws + 90177536);   // 2 MB
  _Float16* Wvh = (_Float16*)(ws + 92274688);   // 2 MB
  _Float16* Woh = (_Float16*)(ws + 94371840);   // 2 MB
  int* klist    = (int*)(ws + 96468992);        // 32 KB
  int* cntp     = (int*)(ws + 96501760);        // 128 B
  int* cntn     = (int*)(ws + 96501888);        // 128 B
  int* idx      = (int*)(ws + 96502016);        // 512 KB
  int* ambr     = (int*)(ws + 97026304);        // 512 KB
  int* ambc     = (int*)(ws + 97550592);        // 128 B
  int* ccnt     = (int*)(ws + 97550720);        // 512 KB
  int* cnd      = (int*)(ws + 98075008);        // 4 MB (end ~97.5 MB)

  hipMemsetAsync(ambc, 0, 4, stream);
  wtrans_kernel<<<dim3(16, 16, 4), 256, 0, stream>>>(Wq, Wk, Wv, Wo,
                                                     Wqh, Wql, Wkh, Wkl, Wvh, Woh);
  scan_kernel<<<BB, 256, 0, stream>>>(mask, klist, cntp, cntn);
  proj_mfma<<<dim3(64, 8, 3), 256, 0, stream>>>(x, Wqh, Wql, Wkh, Wkl, Wvh,
                                                Qhi, Qlo, Khi, Klo, Vh);
  filter_kernel<<<1024, 256, 0, stream>>>(Qhi, Qlo, Khi, Klo, klist, cntp, cntn,
                                          idx, ambr, ambc, cnd, ccnt);
  refine_kernel<<<1024, 256, 0, stream>>>(Qhi, Qlo, Khi, Klo, x, Wq, Wk,
                                          ambr, ambc, cnd, ccnt, idx);
  out_mfma<<<dim3(64, 8), 256, 0, stream>>>(Vh, idx, Woh, bo, ga, be, mm, mv, out);
}

// Round 10
// 452.223 us; speedup vs baseline: 5.4377x; 1.0381x over previous
//
#include <hip/hip_runtime.h>
#include <hip/hip_bf16.h>
#include <float.h>

#define BB 4
#define SS 2048
#define DD 1024
#define HH 16
#define DP 64
#define BKS 32
#define MARGIN_F 0.02f   /* >= 2*packing_ulp(3.9e-3) + 3-pass filter err, 2.5x headroom */
#define TIER2_TAU 1e-4   /* recon-gap below this -> ground-truth re-adjudication */

typedef __attribute__((ext_vector_type(8))) _Float16 half8v;
typedef __attribute__((ext_vector_type(16))) float f32x16;

typedef __attribute__((address_space(3))) void lds_void;
typedef const __attribute__((address_space(1))) void gbl_void;
static __device__ __forceinline__ void gload16(const void* g, void* l) {
  __builtin_amdgcn_global_load_lds((gbl_void*)g, (lds_void*)l, 16, 0, 0);
}

// ---------------------------------------------------------------------------
// Prep: transpose W[k][n] f32 -> Wt[n][k] fp16 hi (+ fp16 lo residual for
// Wq,Wk).  z: 0=Wq(hi+lo) 1=Wk(hi+lo) 2=Wv(hi) 3=Wo(hi).
// ---------------------------------------------------------------------------
__global__ __launch_bounds__(256) void wtrans_kernel(
    const float* __restrict__ Wq, const float* __restrict__ Wk,
    const float* __restrict__ Wv, const float* __restrict__ Wo,
    _Float16* __restrict__ Wqh, _Float16* __restrict__ Wql,
    _Float16* __restrict__ Wkh, _Float16* __restrict__ Wkl,
    _Float16* __restrict__ Wvh, _Float16* __restrict__ Woh)
{
  const int z = blockIdx.z;
  const float* __restrict__ src = (z == 0) ? Wq : (z == 1 ? Wk : (z == 2 ? Wv : Wo));
  _Float16* __restrict__ dh = (z == 0) ? Wqh : (z == 1 ? Wkh : (z == 2 ? Wvh : Woh));
  _Float16* __restrict__ dl = (z == 0) ? Wql : Wkl;
  __shared__ float tile[64][65];
  const int k0 = blockIdx.x * 64, n0 = blockIdx.y * 64;
  const int c = threadIdx.x & 63, rb = threadIdx.x >> 6;
  #pragma unroll
  for (int i = 0; i < 16; ++i)
    tile[rb + 4 * i][c] = src[(size_t)(k0 + rb + 4 * i) * DD + n0 + c];
  __syncthreads();
  #pragma unroll
  for (int i = 0; i < 16; ++i) {
    const int n = n0 + rb + 4 * i;
    const float v = tile[c][rb + 4 * i];
    const _Float16 h = (_Float16)v;
    dh[(size_t)n * DD + k0 + c] = h;
    if (z < 2) dl[(size_t)n * DD + k0 + c] = (_Float16)(v - (float)h);
  }
}

// ---------------------------------------------------------------------------
// LDS-staged fp16 MFMA projection GEMM.  Split mode (Q,K): 8 chunks/row with
// hi chunk c at slot (2c)^(row&7), lo chunk c at slot (2c+1)^(row&7) --
// spreads every wave read/write over all 32 banks (was: hi on banks 0-15
// only -> 2x serialization, 3.1e7 conflict cycles).  B staged via
// global_load_lds with the matching inverse-permuted source.  V: unchanged.
// ---------------------------------------------------------------------------
__global__ __launch_bounds__(256) void proj_mfma(
    const float* __restrict__ x,
    const _Float16* __restrict__ Wqh, const _Float16* __restrict__ Wql,
    const _Float16* __restrict__ Wkh, const _Float16* __restrict__ Wkl,
    const _Float16* __restrict__ Wvh,
    _Float16* __restrict__ Qhi, _Float16* __restrict__ Qlo,
    _Float16* __restrict__ Khi, _Float16* __restrict__ Klo,
    _Float16* __restrict__ Vh)
{
  const int z = blockIdx.z;
  const bool split = (z < 2);
  const _Float16* __restrict__ Wh = (z == 0) ? Wqh : (z == 1 ? Wkh : Wvh);
  const _Float16* __restrict__ Wl = (z == 0) ? Wql : Wkl;
  _Float16* __restrict__ dhi = (z == 0) ? Qhi : (z == 1 ? Khi : Vh);
  _Float16* __restrict__ dlo = (z == 0) ? Qlo : Klo;

  __shared__ _Float16 Asm[8192];
  __shared__ _Float16 Bsm[8192];

  const int rows0 = blockIdx.x * 128, cols0 = blockIdx.y * 128;
  const int t = threadIdx.x;
  const int wid = t >> 6, l = t & 63;
  const int warpR = wid >> 1, warpC = wid & 1;
  const int lr = l & 31, lh = l >> 5;

  f32x16 acc[2][2];
  #pragma unroll
  for (int i = 0; i < 2; ++i)
    #pragma unroll
    for (int j = 0; j < 2; ++j)
      #pragma unroll
      for (int r = 0; r < 16; ++r) acc[i][j][r] = 0.f;

  // ---- A staging constants (reg->ds_write): thread t -> row t>>1, 16 k's
  const int arow = t >> 1;
  const int kc0 = (t & 1) * 2;                 // chunks kc0, kc0+1
  const float* xsrc = x + (size_t)(rows0 + arow) * DD + kc0 * 8;
  int aslot_h0, aslot_h1, aslot_l0, aslot_l1;
  if (split) {
    aslot_h0 = arow * 8 + ((2 * kc0) ^ (arow & 7));
    aslot_h1 = arow * 8 + ((2 * kc0 + 2) ^ (arow & 7));
    aslot_l0 = arow * 8 + ((2 * kc0 + 1) ^ (arow & 7));
    aslot_l1 = arow * 8 + ((2 * kc0 + 3) ^ (arow & 7));
  } else {
    aslot_h0 = arow * 4 + (kc0 ^ ((arow >> 1) & 3));
    aslot_h1 = arow * 4 + ((kc0 + 1) ^ ((arow >> 1) & 3));
    aslot_l0 = aslot_l1 = 0;
  }

  // ---- B staging constants (global_load_lds, dest linear slot = t+i*256)
  const int nbi = split ? 4 : 2;
  const _Float16* bsrc[4];
  #pragma unroll
  for (int i = 0; i < 4; ++i) {
    const int s = t + i * 256;
    int col, wsrc; const _Float16* base;
    if (split) {
      col = s >> 3;
      const int u = (s & 7) ^ (col & 7);
      wsrc = u >> 1;
      base = (u & 1) ? Wl : Wh;
    } else {
      col = (s & 511) >> 2;
      wsrc = (s & 3) ^ ((col >> 1) & 3);
      base = Wh;
    }
    bsrc[i] = base + (size_t)(cols0 + col) * DD + wsrc * 8;
  }

  for (int ks = 0; ks < 32; ++ks) {
    const int k0 = ks * BKS;
    if (ks) __syncthreads();

    #pragma unroll
    for (int i = 0; i < 4; ++i)
      if (i < nbi) gload16(bsrc[i] + k0, &Bsm[(t + i * 256) * 8]);

    {
      const float4 f0 = *(const float4*)(xsrc + k0);
      const float4 f1 = *(const float4*)(xsrc + k0 + 4);
      const float4 f2 = *(const float4*)(xsrc + k0 + 8);
      const float4 f3 = *(const float4*)(xsrc + k0 + 12);
      const float xv[16] = {f0.x, f0.y, f0.z, f0.w, f1.x, f1.y, f1.z, f1.w,
                            f2.x, f2.y, f2.z, f2.w, f3.x, f3.y, f3.z, f3.w};
      half8v h0, h1, lo0, lo1;
      #pragma unroll
      for (int j = 0; j < 8; ++j) {
        h0[j] = (_Float16)xv[j];
        lo0[j] = (_Float16)(xv[j] - (float)h0[j]);
        h1[j] = (_Float16)xv[8 + j];
        lo1[j] = (_Float16)(xv[8 + j] - (float)h1[j]);
      }
      *(half8v*)&Asm[aslot_h0 * 8] = h0;
      *(half8v*)&Asm[aslot_h1 * 8] = h1;
      if (split) {
        *(half8v*)&Asm[aslot_l0 * 8] = lo0;
        *(half8v*)&Asm[aslot_l1 * 8] = lo1;
      }
    }
    __syncthreads();

    #pragma unroll
    for (int kh2 = 0; kh2 < 2; ++kh2) {
      const int c = kh2 * 2 + lh;
      half8v ah[2], alv[2], bh[2], blv[2];
      #pragma unroll
      for (int wr = 0; wr < 2; ++wr) {
        const int row = warpR * 64 + wr * 32 + lr;
        if (split) {
          ah[wr]  = *(const half8v*)&Asm[(row * 8 + ((2 * c) ^ (row & 7))) * 8];
          alv[wr] = *(const half8v*)&Asm[(row * 8 + ((2 * c + 1) ^ (row & 7))) * 8];
        } else {
          ah[wr] = *(const half8v*)&Asm[(row * 4 + (c ^ ((row >> 1) & 3))) * 8];
        }
      }
      #pragma unroll
      for (int wc = 0; wc < 2; ++wc) {
        const int col = warpC * 64 + wc * 32 + lr;
        if (split) {
          bh[wc]  = *(const half8v*)&Bsm[(col * 8 + ((2 * c) ^ (col & 7))) * 8];
          blv[wc] = *(const half8v*)&Bsm[(col * 8 + ((2 * c + 1) ^ (col & 7))) * 8];
        } else {
          bh[wc] = *(const half8v*)&Bsm[(col * 4 + (c ^ ((col >> 1) & 3))) * 8];
        }
      }
      #pragma unroll
      for (int wr = 0; wr < 2; ++wr)
        #pragma unroll
        for (int wc = 0; wc < 2; ++wc) {
          acc[wr][wc] = __builtin_amdgcn_mfma_f32_32x32x16_f16(ah[wr], bh[wc], acc[wr][wc], 0, 0, 0);
          if (split) {
            acc[wr][wc] = __builtin_amdgcn_mfma_f32_32x32x16_f16(alv[wr], bh[wc], acc[wr][wc], 0, 0, 0);
            acc[wr][wc] = __builtin_amdgcn_mfma_f32_32x32x16_f16(ah[wr], blv[wc], acc[wr][wc], 0, 0, 0);
          }
        }
    }
  }

  const int mb0 = rows0 + warpR * 64 + 4 * lh;
  #pragma unroll
  for (int wr = 0; wr < 2; ++wr)
    #pragma unroll
    for (int wc = 0; wc < 2; ++wc) {
      const int n = cols0 + warpC * 64 + wc * 32 + lr;
      const int h = n >> 6, d = n & 63;
      #pragma unroll
      for (int r = 0; r < 16; ++r) {
        const int m = mb0 + wr * 32 + (r & 3) + 8 * (r >> 2);
        const int b = m >> 11, srow = m & 2047;
        const size_t o = ((size_t)(b * HH + h) * SS + srow) * DP + d;
        const float a = acc[wr][wc][r];
        const _Float16 h16 = (_Float16)a;
        dhi[o] = h16;
        if (split) dlo[o] = (_Float16)(a - (float)h16);
      }
    }
}

// ---------------------------------------------------------------------------
// Mask scan -> compact key list padded to x32 with duplicates of the first
// masked key; writes real count (for validity masking) and padded count.
// ---------------------------------------------------------------------------
__global__ __launch_bounds__(256) void scan_kernel(
    const int* __restrict__ mask, int* __restrict__ klist,
    int* __restrict__ cntpad, int* __restrict__ cntreal)
{
  __shared__ int part[256];
  __shared__ int tot;
  const int b = blockIdx.x, t = threadIdx.x;
  int loc[8]; int c = 0;
  #pragma unroll
  for (int j = 0; j < 8; ++j) {
    loc[j] = (mask[(b << 11) + t * 8 + j] == 0);
    c += loc[j];
  }
  part[t] = c;
  __syncthreads();
  if (t == 0) {
    int run = 0;
    for (int i = 0; i < 256; ++i) { int v = part[i]; part[i] = run; run += v; }
    tot = run;
  }
  __syncthreads();
  int off = part[t];
  #pragma unroll
  for (int j = 0; j < 8; ++j)
    if (loc[j]) klist[(b << 11) + off++] = t * 8 + j;
  __syncthreads();
  if (t == 0) {
    int n = tot;
    int first;
    if (n == 0) { klist[b << 11] = 0; n = 1; first = 0; }
    else first = klist[b << 11];
    int np = (n + 31) & ~31;
    for (int i = n; i < np; ++i) klist[(b << 11) + i] = first;
    cntpad[b] = np;
    cntreal[b] = n;
  }
}

// ---------------------------------------------------------------------------
// MFMA masked-argmin filter, 3-pass fp16 hi/lo.  Unchanged.
// ---------------------------------------------------------------------------
__global__ __launch_bounds__(256) void filter_kernel(
    const _Float16* __restrict__ Qhi, const _Float16* __restrict__ Qlo,
    const _Float16* __restrict__ Khi, const _Float16* __restrict__ Klo,
    const int* __restrict__ klist, const int* __restrict__ cntpad,
    const int* __restrict__ cntreal,
    int* __restrict__ idx, int* __restrict__ ambr, int* __restrict__ ambc,
    int* __restrict__ cand, int* __restrict__ ccnt)
{
  const int bh = blockIdx.x >> 4;
  const int b = bh >> 4;
  const int wid = threadIdx.x >> 6;
  const int l = threadIdx.x & 63;
  const int q0 = ((blockIdx.x & 15) << 7) + (wid << 5);
  const int half = l >> 5;
  const int lq = l & 31;
  const int* __restrict__ kl_b = klist + (b << 11);

  half8v qh[4], ql[4];
  {
    const size_t qrow = ((size_t)bh * SS + q0 + lq) * DP + half * 8;
    #pragma unroll
    for (int ds = 0; ds < 4; ++ds) {
      qh[ds] = *(const half8v*)(Qhi + qrow + ds * 16);
      ql[ds] = *(const half8v*)(Qlo + qrow + ds * 16);
    }
  }

  const int nreal = cntreal[b];
  const int nt = cntpad[b] >> 5;
  float m1 = FLT_MAX, m2 = FLT_MAX, m3 = FLT_MAX,
        m4 = FLT_MAX, m5 = FLT_MAX, m6 = FLT_MAX;
  uint kidx[16];
  #pragma unroll
  for (int r = 0; r < 16; ++r)
    kidx[r] = (uint)((r & 3) + ((r >> 2) << 3) + (half << 2));

  const size_t kbase = (size_t)bh * SS;
  for (int t = 0; t < nt; ++t) {
    const int kval = kl_b[(t << 5) + lq];
    const size_t krow = (kbase + kval) * DP + half * 8;
    f32x16 acc;
    #pragma unroll
    for (int r = 0; r < 16; ++r) acc[r] = 0.f;
    #pragma unroll
    for (int ds = 0; ds < 4; ++ds) {
      const half8v kh = *(const half8v*)(Khi + krow + ds * 16);
      const half8v kl = *(const half8v*)(Klo + krow + ds * 16);
      acc = __builtin_amdgcn_mfma_f32_32x32x16_f16(kh, qh[ds], acc, 0, 0, 0);
      acc = __builtin_amdgcn_mfma_f32_32x32x16_f16(kh, ql[ds], acc, 0, 0, 0);
      acc = __builtin_amdgcn_mfma_f32_32x32x16_f16(kl, qh[ds], acc, 0, 0, 0);
    }
    const bool part = (t == nt - 1) && ((nreal & 31) != 0);
    #pragma unroll
    for (int r = 0; r < 16; ++r) {
      const uint pv = (__float_as_uint(acc[r]) & 0xFFFFF800u) | kidx[r];
      float v = __uint_as_float(pv);
      if (part && kidx[r] >= (uint)nreal) v = FLT_MAX;
      m6 = __builtin_amdgcn_fmed3f(v, m5, m6);
      m5 = __builtin_amdgcn_fmed3f(v, m4, m5);
      m4 = __builtin_amdgcn_fmed3f(v, m3, m4);
      m3 = __builtin_amdgcn_fmed3f(v, m2, m3);
      m2 = __builtin_amdgcn_fmed3f(v, m1, m2);
      m1 = fminf(v, m1);
      kidx[r] += 32;
    }
  }

  float om[6];
  om[0] = __shfl_xor(m1, 32, 64);
  om[1] = __shfl_xor(m2, 32, 64);
  om[2] = __shfl_xor(m3, 32, 64);
  om[3] = __shfl_xor(m4, 32, 64);
  om[4] = __shfl_xor(m5, 32, 64);
  om[5] = __shfl_xor(m6, 32, 64);
  #pragma unroll
  for (int j = 0; j < 6; ++j) {
    const float v = om[j];
    m6 = __builtin_amdgcn_fmed3f(v, m5, m6);
    m5 = __builtin_amdgcn_fmed3f(v, m4, m5);
    m4 = __builtin_amdgcn_fmed3f(v, m3, m4);
    m3 = __builtin_amdgcn_fmed3f(v, m2, m3);
    m2 = __builtin_amdgcn_fmed3f(v, m1, m2);
    m1 = fminf(v, m1);
  }

  if (half == 0) {
    const int row = bh * SS + q0 + lq;
    const uint u1 = __float_as_uint(m1);
    const int k1 = kl_b[u1 & 2047u];
    idx[row] = k1;
    const float v1 = __uint_as_float(u1 & 0xFFFFF800u);
    const uint us[5] = {__float_as_uint(m2), __float_as_uint(m3),
                        __float_as_uint(m4), __float_as_uint(m5),
                        __float_as_uint(m6)};
    const float v2 = __uint_as_float(us[0] & 0xFFFFF800u);
    if (v2 - v1 < MARGIN_F) {
      int c[6]; int n = 0;
      c[n++] = k1;
      #pragma unroll
      for (int j = 0; j < 5; ++j) {
        const float vj = __uint_as_float(us[j] & 0xFFFFF800u);
        if (vj - v1 < MARGIN_F) c[n++] = kl_b[us[j] & 2047u];
        else break;
      }
      const int pos = atomicAdd(ambc, 1);
      ambr[pos] = row;
      ccnt[row] = n;
      for (int j = 0; j < n; ++j) cand[row * 8 + j] = c[j];
    }
  }
}

// ---------------------------------------------------------------------------
// Two-tier refine, latency-optimized.  Unchanged from round 9.
// ---------------------------------------------------------------------------
__global__ __launch_bounds__(256) void refine_kernel(
    const _Float16* __restrict__ Qhi, const _Float16* __restrict__ Qlo,
    const _Float16* __restrict__ Khi, const _Float16* __restrict__ Klo,
    const float* __restrict__ x, const float* __restrict__ Wq,
    const float* __restrict__ Wk,
    const int* __restrict__ ambr, const int* __restrict__ ambc,
    const int* __restrict__ cand, const int* __restrict__ ccnt,
    int* __restrict__ idx)
{
  __shared__ double red[4][7][64];
  const int n = *ambc;
  const int t = threadIdx.x;
  const int w = t >> 6, lane = t & 63;

  for (int it = blockIdx.x; it < n; it += gridDim.x) {
    const int row = ambr[it];
    const int bh = row >> 11;
    const int cnum = ccnt[row];

    const size_t qb = (size_t)row * DP;
    const double q = (double)(float)Qhi[qb + lane] + (double)(float)Qlo[qb + lane];
    double best = 1e300, best2 = 1e300; int bi = 0x7fffffff;
    for (int c = 0; c < cnum; ++c) {
      const int k = cand[row * 8 + c] & 2047;
      const size_t kb = ((size_t)bh * SS + k) * DP;
      const double kv = (double)(float)Khi[kb + lane] + (double)(float)Klo[kb + lane];
      double p = q * kv;
      #pragma unroll
      for (int o = 32; o > 0; o >>= 1) p += __shfl_xor(p, o, 64);
      if (p < best) { best2 = best; best = p; bi = k; }
      else if (p < best2) best2 = p;
    }

    if (best2 - best < TIER2_TAU) {
      const int qq = row & 2047;
      const int b = bh >> 4, h = bh & 15;
      const int wc = (h << 6) + lane;
      const float* xq = x + ((size_t)(b << 11) + qq) * DD;
      int kk[6];
      #pragma unroll
      for (int c = 0; c < 6; ++c)
        kk[c] = cand[row * 8 + (c < cnum ? c : 0)] & 2047;
      const float* xk0 = x + ((size_t)(b << 11) + kk[0]) * DD;
      const float* xk1 = x + ((size_t)(b << 11) + kk[1]) * DD;
      const float* xk2 = x + ((size_t)(b << 11) + kk[2]) * DD;
      const float* xk3 = x + ((size_t)(b << 11) + kk[3]) * DD;
      const float* xk4 = x + ((size_t)(b << 11) + kk[4]) * DD;
      const float* xk5 = x + ((size_t)(b << 11) + kk[5]) * DD;

      double qd = 0.0, kd0 = 0.0, kd1 = 0.0, kd2 = 0.0,
             kd3 = 0.0, kd4 = 0.0, kd5 = 0.0;
      const int j0 = w * 256;
      #pragma unroll 4
      for (int j = j0; j < j0 + 256; ++j) {
        const double wq = (double)Wq[(size_t)j * DD + wc];
        const double wk = (double)Wk[(size_t)j * DD + wc];
        qd  = fma((double)xq[j],  wq, qd);
        kd0 = fma((double)xk0[j], wk, kd0);
        kd1 = fma((double)xk1[j], wk, kd1);
        kd2 = fma((double)xk2[j], wk, kd2);
        kd3 = fma((double)xk3[j], wk, kd3);
        kd4 = fma((double)xk4[j], wk, kd4);
        kd5 = fma((double)xk5[j], wk, kd5);
      }
      red[w][0][lane] = qd;
      red[w][1][lane] = kd0; red[w][2][lane] = kd1; red[w][3][lane] = kd2;
      red[w][4][lane] = kd3; red[w][5][lane] = kd4; red[w][6][lane] = kd5;
      __syncthreads();

      if (w == 0) {
        const double qs = red[0][0][lane] + red[1][0][lane] +
                          red[2][0][lane] + red[3][0][lane];
        best = 1e300; bi = 0x7fffffff;
        for (int c = 0; c < cnum; ++c) {
          const double ks = red[0][1 + c][lane] + red[1][1 + c][lane] +
                            red[2][1 + c][lane] + red[3][1 + c][lane];
          double p = qs * ks;
          #pragma unroll
          for (int o = 32; o > 0; o >>= 1) p += __shfl_xor(p, o, 64);
          const int k = kk[c];
          if (p < best || (p == best && k < bi)) { best = p; bi = k; }
        }
        if (lane == 0) idx[row] = bi;
      }
      __syncthreads();
    } else {
      if (t == 0) idx[row] = bi;
    }
  }
}

// ---------------------------------------------------------------------------
// fp16 MFMA out-projection.  Unchanged.
// ---------------------------------------------------------------------------
__global__ __launch_bounds__(256) void out_mfma(
    const _Float16* __restrict__ Vh, const int* __restrict__ idx,
    const _Float16* __restrict__ Woh, const float* __restrict__ bo,
    const float* __restrict__ gamma, const float* __restrict__ beta,
    const float* __restrict__ mmean, const float* __restrict__ mvar,
    float* __restrict__ out)
{
  const int rows0 = blockIdx.x * 128, cols0 = blockIdx.y * 128;
  const int w = threadIdx.x >> 6, l = threadIdx.x & 63;
  const int lr = l & 31, hi8 = (l >> 5) * 8;
  const int m = rows0 + w * 32 + lr;
  const int b = m >> 11, srow = m & 2047;

  int vidx[16];
  #pragma unroll
  for (int h = 0; h < 16; ++h)
    vidx[h] = idx[(size_t)(b * HH + h) * SS + srow];

  size_t brow[4];
  #pragma unroll
  for (int cf = 0; cf < 4; ++cf)
    brow[cf] = (size_t)(cols0 + cf * 32 + lr) * DD + hi8;

  f32x16 acc[4];
  #pragma unroll
  for (int cf = 0; cf < 4; ++cf)
    #pragma unroll
    for (int r = 0; r < 16; ++r) acc[cf][r] = 0.f;

  #pragma unroll 4
  for (int s = 0; s < 64; ++s) {
    const int h = s >> 2;
    const int kk = (s & 3) * 16 + hi8;
    half8v a = *(const half8v*)(Vh + ((size_t)(b * HH + h) * SS + vidx[h]) * DP + kk);
    #pragma unroll
    for (int cf = 0; cf < 4; ++cf) {
      half8v bf = *(const half8v*)(Woh + brow[cf] + s * 16);
      acc[cf] = __builtin_amdgcn_mfma_f32_32x32x16_f16(a, bf, acc[cf], 0, 0, 0);
    }
  }

  const int m_base = rows0 + w * 32 + 4 * (l >> 5);
  #pragma unroll
  for (int cf = 0; cf < 4; ++cf) {
    const int n = cols0 + cf * 32 + lr;
    const float sc = gamma[n] * rsqrtf(mvar[n] + 1e-3f);
    const float ofs = (bo[n] - mmean[n]) * sc + beta[n];
    #pragma unroll
    for (int r = 0; r < 16; ++r) {
      const int mr = m_base + (r & 3) + 8 * (r >> 2);
      out[(size_t)mr * DD + n] = acc[cf][r] * sc + ofs;
    }
  }
}

// ---------------------------------------------------------------------------
extern "C" void kernel_launch(void* const* d_in, const int* in_sizes, int n_in,
                              void* d_out, int out_size, void* d_ws, size_t ws_size,
                              hipStream_t stream)
{
  const float* x  = (const float*)d_in[0];
  const int* mask = (const int*)d_in[1];
  const float* Wq = (const float*)d_in[2];
  const float* Wk = (const float*)d_in[3];
  const float* Wv = (const float*)d_in[4];
  const float* Wo = (const float*)d_in[5];
  const float* bo = (const float*)d_in[6];
  const float* ga = (const float*)d_in[7];
  const float* be = (const float*)d_in[8];
  const float* mm = (const float*)d_in[9];
  const float* mv = (const float*)d_in[10];
  float* out = (float*)d_out;

  char* ws = (char*)d_ws;
  _Float16* Qhi = (_Float16*)(ws + 0);          // 16 MB
  _Float16* Qlo = (_Float16*)(ws + 16777216);   // 16 MB
  _Float16* Khi = (_Float16*)(ws + 33554432);   // 16 MB
  _Float16* Klo = (_Float16*)(ws + 50331648);   // 16 MB
  _Float16* Vh  = (_Float16*)(ws + 67108864);   // 16 MB
  _Float16* Wqh = (_Float16*)(ws + 83886080);   // 2 MB
  _Float16* Wql = (_Float16*)(ws + 85983232);   // 2 MB
  _Float16* Wkh = (_Float16*)(ws + 88080384);   // 2 MB
  _Float16* Wkl = (_Float16*)(ws + 90177536);   // 2 MB
  _Float16* Wvh = (_Float16*)(ws + 92274688);   // 2 MB
  _Float16* Woh = (_Float16*)(ws + 94371840);   // 2 MB
  int* klist    = (int*)(ws + 96468992);        // 32 KB
  int* cntp     = (int*)(ws + 96501760);        // 128 B
  int* cntn     = (int*)(ws + 96501888);        // 128 B
  int* idx      = (int*)(ws + 96502016);        // 512 KB
  int* ambr     = (int*)(ws + 97026304);        // 512 KB
  int* ambc     = (int*)(ws + 97550592);        // 128 B
  int* ccnt     = (int*)(ws + 97550720);        // 512 KB
  int* cnd      = (int*)(ws + 98075008);        // 4 MB (end ~97.5 MB)

  hipMemsetAsync(ambc, 0, 4, stream);
  wtrans_kernel<<<dim3(16, 16, 4), 256, 0, stream>>>(Wq, Wk, Wv, Wo,
                                                     Wqh, Wql, Wkh, Wkl, Wvh, Woh);
  scan_kernel<<<BB, 256, 0, stream>>>(mask, klist, cntp, cntn);
  proj_mfma<<<dim3(64, 8, 3), 256, 0, stream>>>(x, Wqh, Wql, Wkh, Wkl, Wvh,
                                                Qhi, Qlo, Khi, Klo, Vh);
  filter_kernel<<<1024, 256, 0, stream>>>(Qhi, Qlo, Khi, Klo, klist, cntp, cntn,
                                          idx, ambr, ambc, cnd, ccnt);
  refine_kernel<<<1024, 256, 0, stream>>>(Qhi, Qlo, Khi, Klo, x, Wq, Wk,
                                          ambr, ambc, cnd, ccnt, idx);
  out_mfma<<<dim3(64, 8), 256, 0, stream>>>(Vh, idx, Woh, bo, ga, be, mm, mv, out);
}